// Round 1
// baseline (627.474 us; speedup 1.0000x reference)
//
#include <hip/hip_runtime.h>

constexpr int KDIM = 256;   // input feature dim
constexpr int HDIM = 128;   // output feature dim

// ---------------- degree / normalization ----------------

__global__ void zero_deg_kernel(int* __restrict__ deg, int n) {
    int i = blockIdx.x * blockDim.x + threadIdx.x;
    if (i < n) deg[i] = 0;
}

__global__ void count_deg_kernel(const int* __restrict__ col, int* __restrict__ deg, int e) {
    int i = blockIdx.x * blockDim.x + threadIdx.x;
    if (i < e) atomicAdd(&deg[col[i]], 1);
}

__global__ void dinv_kernel(const int* __restrict__ deg, float* __restrict__ dinv, int n) {
    int i = blockIdx.x * blockDim.x + threadIdx.x;
    if (i < n) dinv[i] = rsqrtf((float)(deg[i] + 1));  // +1 = self loop
}

// ---------------- exclusive scan (single block, 1024 threads) ----------------

__global__ void scan_kernel(const int* __restrict__ deg, int* __restrict__ offs,
                            int* __restrict__ cursor, int n) {
    __shared__ int wsum[16];
    __shared__ int s_carry;
    int tid = threadIdx.x;
    int lane = tid & 63, wid = tid >> 6;
    if (tid == 0) s_carry = 0;
    __syncthreads();
    for (int base = 0; base < n; base += 1024) {
        int i = base + tid;
        int v = (i < n) ? deg[i] : 0;
        int incl = v;
        #pragma unroll
        for (int d = 1; d < 64; d <<= 1) {
            int t = __shfl_up(incl, d, 64);
            if (lane >= d) incl += t;
        }
        if (lane == 63) wsum[wid] = incl;
        __syncthreads();
        int carry = s_carry;
        int woff = 0;
        #pragma unroll
        for (int w = 0; w < 16; ++w)
            if (w < wid) woff += wsum[w];
        int excl = carry + woff + incl - v;
        if (i < n) { offs[i] = excl; cursor[i] = excl; }
        __syncthreads();
        if (tid == 1023) s_carry = carry + woff + incl;  // carry + chunk total
        __syncthreads();
    }
}

// ---------------- CSR scatter (counting sort by destination) ----------------

__global__ void scatter_kernel(const int* __restrict__ row, const int* __restrict__ col,
                               int* __restrict__ cursor, int* __restrict__ csr, int e) {
    int i = blockIdx.x * blockDim.x + threadIdx.x;
    if (i < e) {
        int c = col[i];
        int p = atomicAdd(&cursor[c], 1);
        csr[p] = row[i];
    }
}

// ---------------- GEMM: hs = (x @ W) * dinv[row] ----------------
// 128 rows x 128 cols per block, 256 threads, 8x8 micro-tile / thread.

__global__ __launch_bounds__(256) void gemm_kernel(
    const float* __restrict__ x, const float* __restrict__ W,
    const float* __restrict__ dinv, float* __restrict__ hs, int n) {
    constexpr int KC = 16;
    __shared__ float xT[KC][132];     // [k][row], padded (staging writes 2-way = free)
    __shared__ float Wt[KC * 128];    // [k][col], same layout as global chunk

    int t = threadIdx.x;
    int tx = t & 15, ty = t >> 4;     // tx: col group, ty: row group
    int blockRow = blockIdx.x * 128;

    float acc[8][8];
    #pragma unroll
    for (int i = 0; i < 8; ++i)
        #pragma unroll
        for (int j = 0; j < 8; ++j) acc[i][j] = 0.f;

    // staging mapping: each thread loads 8 consecutive k-floats of one row
    int srow = t >> 1;                // 0..127
    int skq = t & 1;                  // which 8-float half of the 16-k chunk
    int grow = blockRow + srow;
    if (grow >= n) grow = n - 1;      // clamp (stores guarded later)
    const float* xg = x + (size_t)grow * KDIM;

    for (int k0 = 0; k0 < KDIM; k0 += KC) {
        float4 xa = *(const float4*)(xg + k0 + skq * 8);
        float4 xb = *(const float4*)(xg + k0 + skq * 8 + 4);
        float4 wa = *(const float4*)(W + k0 * 128 + t * 4);
        float4 wb = *(const float4*)(W + k0 * 128 + 1024 + t * 4);
        __syncthreads();              // previous iter's LDS reads done
        xT[skq * 8 + 0][srow] = xa.x; xT[skq * 8 + 1][srow] = xa.y;
        xT[skq * 8 + 2][srow] = xa.z; xT[skq * 8 + 3][srow] = xa.w;
        xT[skq * 8 + 4][srow] = xb.x; xT[skq * 8 + 5][srow] = xb.y;
        xT[skq * 8 + 6][srow] = xb.z; xT[skq * 8 + 7][srow] = xb.w;
        *(float4*)(Wt + t * 4) = wa;
        *(float4*)(Wt + 1024 + t * 4) = wb;
        __syncthreads();
        #pragma unroll
        for (int k = 0; k < KC; ++k) {
            float4 a0 = *(const float4*)&xT[k][ty * 4];
            float4 a1 = *(const float4*)&xT[k][64 + ty * 4];
            float4 b0 = *(const float4*)&Wt[k * 128 + tx * 4];
            float4 b1 = *(const float4*)&Wt[k * 128 + 64 + tx * 4];
            float av[8] = {a0.x, a0.y, a0.z, a0.w, a1.x, a1.y, a1.z, a1.w};
            float bv[8] = {b0.x, b0.y, b0.z, b0.w, b1.x, b1.y, b1.z, b1.w};
            #pragma unroll
            for (int i = 0; i < 8; ++i)
                #pragma unroll
                for (int j = 0; j < 8; ++j)
                    acc[i][j] += av[i] * bv[j];
        }
    }

    #pragma unroll
    for (int half = 0; half < 2; ++half) {
        #pragma unroll
        for (int i = 0; i < 4; ++i) {
            int r = blockRow + half * 64 + ty * 4 + i;
            if (r < n) {
                float d = dinv[r];
                int ai = half * 4 + i;
                float4 o0 = make_float4(acc[ai][0] * d, acc[ai][1] * d,
                                        acc[ai][2] * d, acc[ai][3] * d);
                float4 o1 = make_float4(acc[ai][4] * d, acc[ai][5] * d,
                                        acc[ai][6] * d, acc[ai][7] * d);
                *(float4*)(hs + (size_t)r * HDIM + tx * 4) = o0;
                *(float4*)(hs + (size_t)r * HDIM + 64 + tx * 4) = o1;
            }
        }
    }
}

// ---------------- aggregation: one wave per destination node ----------------
// out[c] = PReLU( dinv[c] * (sum_{e in in(c)} hs[src_e] + hs[c]) + b )

__global__ __launch_bounds__(256) void aggregate_kernel(
    const float* __restrict__ hs, const int* __restrict__ offs,
    const int* __restrict__ deg, const int* __restrict__ csr,
    const float* __restrict__ dinv, const float* __restrict__ b,
    const float* __restrict__ alpha, float* __restrict__ out, int n) {
    int wid = threadIdx.x >> 6;
    int lane = threadIdx.x & 63;
    int node = blockIdx.x * 4 + wid;
    if (node >= n) return;
    int base = offs[node];
    int cnt = deg[node];
    int ch = lane * 2;                // each lane owns 2 channels (float2)
    float2 acc = *(const float2*)(hs + (size_t)node * HDIM + ch);  // self loop
    for (int j = 0; j < cnt; j += 64) {
        int m = min(cnt - j, 64);
        int idx = 0;
        if (lane < m) idx = csr[base + j + lane];  // coalesced src batch
        for (int tt = 0; tt < m; ++tt) {
            int s = __shfl(idx, tt, 64);
            float2 v = *(const float2*)(hs + (size_t)s * HDIM + ch);
            acc.x += v.x; acc.y += v.y;
        }
    }
    float dc = dinv[node];
    float2 bb = *(const float2*)(b + ch);
    float2 aa = *(const float2*)(alpha + ch);
    float o0 = fmaf(dc, acc.x, bb.x);
    float o1 = fmaf(dc, acc.y, bb.y);
    o0 = o0 >= 0.f ? o0 : aa.x * o0;
    o1 = o1 >= 0.f ? o1 : aa.y * o1;
    *(float2*)(out + (size_t)node * HDIM + ch) = make_float2(o0, o1);
}

// ---------------- launch ----------------

extern "C" void kernel_launch(void* const* d_in, const int* in_sizes, int n_in,
                              void* d_out, int out_size, void* d_ws, size_t ws_size,
                              hipStream_t stream) {
    const float* x     = (const float*)d_in[0];
    const int*   ei    = (const int*)d_in[1];
    const float* W     = (const float*)d_in[2];
    const float* b     = (const float*)d_in[3];
    const float* alpha = (const float*)d_in[4];
    float* out = (float*)d_out;

    int E = in_sizes[1] / 2;
    int N = in_sizes[0] / KDIM;

    // workspace layout: hs[N*128] f32 | dinv[N] f32 | deg[N] | offs[N] | cursor[N] | csr[E]
    float* hs   = (float*)d_ws;
    float* dinv = hs + (size_t)N * HDIM;
    int* deg    = (int*)(dinv + N);
    int* offs   = deg + N;
    int* cursor = offs + N;
    int* csr    = cursor + N;

    const int* rowp = ei;      // edge_index[0] = sources
    const int* colp = ei + E;  // edge_index[1] = destinations

    int bn = (N + 255) / 256;
    int be = (E + 255) / 256;

    hipLaunchKernelGGL(zero_deg_kernel,  dim3(bn), dim3(256), 0, stream, deg, N);
    hipLaunchKernelGGL(count_deg_kernel, dim3(be), dim3(256), 0, stream, colp, deg, E);
    hipLaunchKernelGGL(dinv_kernel,      dim3(bn), dim3(256), 0, stream, deg, dinv, N);
    hipLaunchKernelGGL(scan_kernel,      dim3(1),  dim3(1024), 0, stream, deg, offs, cursor, N);
    hipLaunchKernelGGL(scatter_kernel,   dim3(be), dim3(256), 0, stream, rowp, colp, cursor, csr, E);
    hipLaunchKernelGGL(gemm_kernel,      dim3((N + 127) / 128), dim3(256), 0, stream, x, W, dinv, hs, N);
    hipLaunchKernelGGL(aggregate_kernel, dim3((N + 3) / 4), dim3(256), 0, stream,
                       hs, offs, deg, csr, dinv, b, alpha, out, N);
}

// Round 2
// 446.827 us; speedup vs baseline: 1.4043x; 1.4043x over previous
//
#include <hip/hip_runtime.h>

constexpr int KDIM = 256;   // input feature dim
constexpr int HDIM = 128;   // output feature dim
constexpr int SC_P = 8;     // scatter destination partitions

typedef __bf16 bf16x8 __attribute__((ext_vector_type(8)));
typedef float  f32x4  __attribute__((ext_vector_type(4)));

__device__ __forceinline__ ushort f2bf(float f) {
    unsigned u = __float_as_uint(f);
    unsigned r = (u + 0x7fffu + ((u >> 16) & 1u)) >> 16;   // RNE
    return (ushort)r;
}

// ---------------- prep: Wt in B-fragment layout (bf16) + zero deg ----------------
// Wt frag layout: g = (c*8 + nf)*64 + lane holds 8 contiguous-k bf16:
//   k = c*32 + (lane>>4)*8 + j,  n = nf*16 + (lane&15)
__global__ __launch_bounds__(256) void prep_kernel(const float* __restrict__ W,
                                                   ushort* __restrict__ Wt,
                                                   int* __restrict__ deg, int n) {
    int b = blockIdx.x, t = threadIdx.x;
    if (b < 16) {
        int g = b * 256 + t;            // [0, 4096)
        int lane = g & 63, cn = g >> 6; // cn = c*8+nf
        int c = cn >> 3, nf = cn & 7;
        int ncol = nf * 16 + (lane & 15);
        int k0 = c * 32 + (lane >> 4) * 8;
        ushort* dst = Wt + (size_t)g * 8;
        #pragma unroll
        for (int j = 0; j < 8; ++j) dst[j] = f2bf(W[(k0 + j) * HDIM + ncol]);
    } else {
        int i = (b - 16) * 256 + t;
        if (i < n) deg[i] = 0;
    }
}

__global__ void count_deg_kernel(const int* __restrict__ col, int* __restrict__ deg, int e) {
    int i = blockIdx.x * blockDim.x + threadIdx.x;
    if (i < e) atomicAdd(&deg[col[i]], 1);
}

// ---------------- hierarchical scan ----------------

__global__ __launch_bounds__(256) void scanA_kernel(const int* __restrict__ deg,
                                                    float* __restrict__ dinv,
                                                    int* __restrict__ partial, int n) {
    int t = threadIdx.x, base = blockIdx.x * 1024;
    int s = 0;
    #pragma unroll
    for (int j = 0; j < 4; ++j) {
        int i = base + j * 256 + t;
        if (i < n) { int d = deg[i]; s += d; dinv[i] = rsqrtf((float)(d + 1)); }
    }
    __shared__ int ws[4];
    #pragma unroll
    for (int d = 1; d < 64; d <<= 1) s += __shfl_xor(s, d, 64);
    int lane = t & 63, w = t >> 6;
    if (lane == 0) ws[w] = s;
    __syncthreads();
    if (t == 0) partial[blockIdx.x] = ws[0] + ws[1] + ws[2] + ws[3];
}

__global__ void scanB_kernel(int* __restrict__ partial, int nb) {  // nb <= 256, 1 block
    int t = threadIdx.x;
    int v = (t < nb) ? partial[t] : 0;
    int orig = v;
    int lane = t & 63, w = t >> 6;
    #pragma unroll
    for (int d = 1; d < 64; d <<= 1) { int u = __shfl_up(v, d, 64); if (lane >= d) v += u; }
    __shared__ int ws[4];
    if (lane == 63) ws[w] = v;
    __syncthreads();
    int add = 0;
    #pragma unroll
    for (int i = 0; i < 4; ++i) if (i < w) add += ws[i];
    if (t < nb) partial[t] = v + add - orig;   // exclusive
}

__global__ __launch_bounds__(256) void scanC_kernel(const int* __restrict__ deg,
                                                    const int* __restrict__ partial,
                                                    int* __restrict__ offs,
                                                    int* __restrict__ cursor, int n) {
    int t = threadIdx.x, base = blockIdx.x * 1024;
    int vals[4], tsum = 0;
    #pragma unroll
    for (int j = 0; j < 4; ++j) {
        int i = base + t * 4 + j;
        vals[j] = (i < n) ? deg[i] : 0;
        tsum += vals[j];
    }
    int lane = t & 63, w = t >> 6;
    int incl = tsum;
    #pragma unroll
    for (int d = 1; d < 64; d <<= 1) { int u = __shfl_up(incl, d, 64); if (lane >= d) incl += u; }
    __shared__ int ws[4];
    if (lane == 63) ws[w] = incl;
    __syncthreads();
    int add = partial[blockIdx.x];
    #pragma unroll
    for (int i = 0; i < 4; ++i) if (i < w) add += ws[i];
    int run = add + incl - tsum;
    #pragma unroll
    for (int j = 0; j < 4; ++j) {
        int i = base + t * 4 + j;
        if (i < n) { offs[i] = run; cursor[i] = run; }
        run += vals[j];
    }
}

// ---------------- destination-partitioned scatter ----------------
// Pass p handles dest in [N*p/P, N*(p+1)/P): csr writes land in one contiguous
// ~(E/P) region that stays L2-resident -> full-line writebacks.

__global__ __launch_bounds__(256) void scatter_kernel(const int* __restrict__ row,
                                                      const int* __restrict__ col,
                                                      int* __restrict__ cursor,
                                                      int* __restrict__ csr,
                                                      int e, int n, int bp) {
    int p = blockIdx.x / bp;
    int cblk = blockIdx.x % bp;
    int lo = (int)(((long long)n * p) / SC_P);
    int hi = (int)(((long long)n * (p + 1)) / SC_P);
    int base = cblk * 1024;
    #pragma unroll
    for (int j = 0; j < 4; ++j) {
        int i = base + j * 256 + threadIdx.x;
        if (i < e) {
            int d = col[i];
            if (d >= lo && d < hi) {
                int pos = atomicAdd(&cursor[d], 1);
                csr[pos] = row[i];
            }
        }
    }
}

// ---------------- GEMM: hsb = bf16( (x @ W) * dinv[row] ), MFMA 16x16x32 ----------------
// Block: 256 threads (4 waves), 64 rows. Wave w owns cols [w*32, w*32+32);
// all B-frags (16 per wave, 64 VGPRs) register-resident from pre-formatted Wt.

constexpr int MT = 64;
constexpr int XS_STRIDE = 264;   // bf16 elems per LDS row (528B: 16B-aligned, pad vs 512)

__global__ __launch_bounds__(256) void gemm_kernel(const float* __restrict__ x,
                                                   const ushort* __restrict__ Wt,
                                                   const float* __restrict__ dinv,
                                                   ushort* __restrict__ hsb, int n) {
    __shared__ ushort xs[MT * XS_STRIDE];
    __shared__ float sdinv[MT];
    int t = threadIdx.x, lane = t & 63, w = t >> 6;
    int row0 = blockIdx.x * MT;

    // B fragments: bfrag[c][f] covers k in [c*32,c*32+32), n in [w*32+f*16, +16)
    bf16x8 bfrag[8][2];
    #pragma unroll
    for (int c = 0; c < 8; ++c)
        #pragma unroll
        for (int f = 0; f < 2; ++f)
            bfrag[c][f] = *(const bf16x8*)(Wt + (size_t)(((c * 8) + (w * 2 + f)) * 64 + lane) * 8);

    // stage x tile (f32 -> bf16): thread t handles row t>>2, k quarter t&3
    {
        int r = t >> 2, q = t & 3;
        int gr = row0 + r; if (gr >= n) gr = n - 1;
        const float* xp = x + (size_t)gr * KDIM + q * 64;
        ushort* dst = xs + r * XS_STRIDE + q * 64;
        #pragma unroll
        for (int i = 0; i < 16; ++i) {
            float4 v = *(const float4*)(xp + i * 4);
            ushort4 o;
            o.x = f2bf(v.x); o.y = f2bf(v.y); o.z = f2bf(v.z); o.w = f2bf(v.w);
            *(ushort4*)(dst + i * 4) = o;
        }
        if (t < MT) { int g = row0 + t; sdinv[t] = dinv[(g < n) ? g : (n - 1)]; }
    }
    __syncthreads();

    #pragma unroll
    for (int s = 0; s < MT / 16; ++s) {
        f32x4 acc0 = {0.f, 0.f, 0.f, 0.f}, acc1 = {0.f, 0.f, 0.f, 0.f};
        #pragma unroll
        for (int c = 0; c < 8; ++c) {
            const ushort* ap = xs + (s * 16 + (lane & 15)) * XS_STRIDE + c * 32 + (lane >> 4) * 8;
            bf16x8 afrag = *(const bf16x8*)ap;
            acc0 = __builtin_amdgcn_mfma_f32_16x16x32_bf16(afrag, bfrag[c][0], acc0, 0, 0, 0);
            acc1 = __builtin_amdgcn_mfma_f32_16x16x32_bf16(afrag, bfrag[c][1], acc1, 0, 0, 0);
        }
        // C/D: col = lane&15, row = (lane>>4)*4 + reg  [m89-verified]
        #pragma unroll
        for (int reg = 0; reg < 4; ++reg) {
            int rl = s * 16 + (lane >> 4) * 4 + reg;
            int gr = row0 + rl;
            if (gr < n) {
                float d = sdinv[rl];
                int col0 = w * 32 + (lane & 15);
                hsb[(size_t)gr * HDIM + col0]      = f2bf(acc0[reg] * d);
                hsb[(size_t)gr * HDIM + col0 + 16] = f2bf(acc1[reg] * d);
            }
        }
    }
}

// ---------------- aggregation: one wave per destination node, bf16 gathers ----------------

__global__ __launch_bounds__(256) void aggregate_kernel(
    const ushort* __restrict__ hsb, const int* __restrict__ offs,
    const int* __restrict__ deg, const int* __restrict__ csr,
    const float* __restrict__ dinv, const float* __restrict__ b,
    const float* __restrict__ alpha, float* __restrict__ out, int n) {
    int wv = threadIdx.x >> 6, lane = threadIdx.x & 63;
    int node = blockIdx.x * 4 + wv;
    if (node >= n) return;
    int base = offs[node], cnt = deg[node];
    const uint* hs32 = (const uint*)hsb;            // 2 bf16 channels per uint
    uint u = hs32[(size_t)node * 64 + lane];        // self loop
    float ax = __uint_as_float(u << 16);
    float ay = __uint_as_float(u & 0xffff0000u);
    for (int j = 0; j < cnt; j += 64) {
        int m = min(cnt - j, 64);
        int idx = (lane < m) ? csr[base + j + lane] : 0;
        for (int tt = 0; tt < m; ++tt) {
            int s = __shfl(idx, tt, 64);
            uint v = hs32[(size_t)s * 64 + lane];
            ax += __uint_as_float(v << 16);
            ay += __uint_as_float(v & 0xffff0000u);
        }
    }
    float dc = dinv[node];
    int ch = lane * 2;
    float o0 = fmaf(dc, ax, b[ch]);
    float o1 = fmaf(dc, ay, b[ch + 1]);
    o0 = o0 >= 0.f ? o0 : alpha[ch] * o0;
    o1 = o1 >= 0.f ? o1 : alpha[ch + 1] * o1;
    *(float2*)(out + (size_t)node * HDIM + ch) = make_float2(o0, o1);
}

// ---------------- launch ----------------

extern "C" void kernel_launch(void* const* d_in, const int* in_sizes, int n_in,
                              void* d_out, int out_size, void* d_ws, size_t ws_size,
                              hipStream_t stream) {
    const float* x     = (const float*)d_in[0];
    const int*   ei    = (const int*)d_in[1];
    const float* W     = (const float*)d_in[2];
    const float* b     = (const float*)d_in[3];
    const float* alpha = (const float*)d_in[4];
    float* out = (float*)d_out;

    int E = in_sizes[1] / 2;
    int N = in_sizes[0] / KDIM;

    // workspace: hsb bf16[N*128] | Wt bf16[32768] | dinv f32[N] | deg/offs/cursor int[N] | partial[512] | csr[E]
    ushort* hsb = (ushort*)d_ws;
    ushort* Wt  = hsb + (size_t)N * HDIM;
    float* dinv = (float*)(Wt + 32768);
    int* deg    = (int*)(dinv + N);
    int* offs   = deg + N;
    int* cursor = offs + N;
    int* partial = cursor + N;
    int* csr    = partial + 512;

    const int* rowp = ei;      // sources
    const int* colp = ei + E;  // destinations

    int nb = (N + 1023) / 1024;
    int bp = (E + 1023) / 1024;

    hipLaunchKernelGGL(prep_kernel,      dim3(16 + (N + 255) / 256), dim3(256), 0, stream, W, Wt, deg, N);
    hipLaunchKernelGGL(count_deg_kernel, dim3((E + 255) / 256), dim3(256), 0, stream, colp, deg, E);
    hipLaunchKernelGGL(scanA_kernel,     dim3(nb), dim3(256), 0, stream, deg, dinv, partial, N);
    hipLaunchKernelGGL(scanB_kernel,     dim3(1),  dim3(256), 0, stream, partial, nb);
    hipLaunchKernelGGL(scanC_kernel,     dim3(nb), dim3(256), 0, stream, deg, partial, offs, cursor, N);
    hipLaunchKernelGGL(scatter_kernel,   dim3(SC_P * bp), dim3(256), 0, stream, rowp, colp, cursor, csr, E, N, bp);
    hipLaunchKernelGGL(gemm_kernel,      dim3((N + MT - 1) / MT), dim3(256), 0, stream, x, Wt, dinv, hsb, N);
    hipLaunchKernelGGL(aggregate_kernel, dim3((N + 3) / 4), dim3(256), 0, stream,
                       hsb, offs, deg, csr, dinv, b, alpha, out, N);
}

// Round 3
// 436.246 us; speedup vs baseline: 1.4384x; 1.0243x over previous
//
#include <hip/hip_runtime.h>

constexpr int KDIM = 256;   // input feature dim
constexpr int HDIM = 128;   // output feature dim
constexpr int SC_P = 4;     // scatter destination partitions

typedef __bf16 bf16x8 __attribute__((ext_vector_type(8)));
typedef float  f32x4  __attribute__((ext_vector_type(4)));

__device__ __forceinline__ ushort f2bf(float f) {
    unsigned u = __float_as_uint(f);
    unsigned r = (u + 0x7fffu + ((u >> 16) & 1u)) >> 16;   // RNE
    return (ushort)r;
}

__device__ __forceinline__ void accum8(float* a, uint4 u) {
    a[0] += __uint_as_float(u.x << 16); a[1] += __uint_as_float(u.x & 0xffff0000u);
    a[2] += __uint_as_float(u.y << 16); a[3] += __uint_as_float(u.y & 0xffff0000u);
    a[4] += __uint_as_float(u.z << 16); a[5] += __uint_as_float(u.z & 0xffff0000u);
    a[6] += __uint_as_float(u.w << 16); a[7] += __uint_as_float(u.w & 0xffff0000u);
}

// ---------------- prep: Wt in B-fragment layout (bf16) + zero deg + zero row ----------------
// Wt frag layout: g = (c*8 + nf)*64 + lane holds 8 contiguous-k bf16:
//   k = c*32 + (lane>>4)*8 + j,  n = nf*16 + (lane&15)
__global__ __launch_bounds__(256) void prep_kernel(const float* __restrict__ W,
                                                   ushort* __restrict__ Wt,
                                                   ushort* __restrict__ hsb,
                                                   int* __restrict__ deg, int n) {
    int b = blockIdx.x, t = threadIdx.x;
    if (b < 16) {
        int g = b * 256 + t;            // [0, 4096)
        int lane = g & 63, cn = g >> 6; // cn = c*8+nf
        int c = cn >> 3, nf = cn & 7;
        int ncol = nf * 16 + (lane & 15);
        int k0 = c * 32 + (lane >> 4) * 8;
        ushort* dst = Wt + (size_t)g * 8;
        #pragma unroll
        for (int j = 0; j < 8; ++j) dst[j] = f2bf(W[(k0 + j) * HDIM + ncol]);
    } else if (b == 16) {
        if (t < HDIM) hsb[(size_t)n * HDIM + t] = 0;   // zero row for masked gathers
    } else {
        int i = (b - 17) * 256 + t;
        if (i < n) deg[i] = 0;
    }
}

__global__ void count_deg_kernel(const int* __restrict__ col, int* __restrict__ deg, int e) {
    int i = blockIdx.x * blockDim.x + threadIdx.x;
    if (i < e) atomicAdd(&deg[col[i]], 1);
}

// ---------------- hierarchical scan ----------------

__global__ __launch_bounds__(256) void scanA_kernel(const int* __restrict__ deg,
                                                    float* __restrict__ dinv,
                                                    int* __restrict__ partial, int n) {
    int t = threadIdx.x, base = blockIdx.x * 1024;
    int s = 0;
    #pragma unroll
    for (int j = 0; j < 4; ++j) {
        int i = base + j * 256 + t;
        if (i < n) { int d = deg[i]; s += d; dinv[i] = rsqrtf((float)(d + 1)); }
    }
    __shared__ int ws[4];
    #pragma unroll
    for (int d = 1; d < 64; d <<= 1) s += __shfl_xor(s, d, 64);
    int lane = t & 63, w = t >> 6;
    if (lane == 0) ws[w] = s;
    __syncthreads();
    if (t == 0) partial[blockIdx.x] = ws[0] + ws[1] + ws[2] + ws[3];
}

__global__ void scanB_kernel(int* __restrict__ partial, int nb) {  // nb <= 256, 1 block
    int t = threadIdx.x;
    int v = (t < nb) ? partial[t] : 0;
    int orig = v;
    int lane = t & 63, w = t >> 6;
    #pragma unroll
    for (int d = 1; d < 64; d <<= 1) { int u = __shfl_up(v, d, 64); if (lane >= d) v += u; }
    __shared__ int ws[4];
    if (lane == 63) ws[w] = v;
    __syncthreads();
    int add = 0;
    #pragma unroll
    for (int i = 0; i < 4; ++i) if (i < w) add += ws[i];
    if (t < nb) partial[t] = v + add - orig;   // exclusive
}

__global__ __launch_bounds__(256) void scanC_kernel(const int* __restrict__ deg,
                                                    const int* __restrict__ partial,
                                                    int* __restrict__ offs,
                                                    int* __restrict__ cursor, int n) {
    int t = threadIdx.x, base = blockIdx.x * 1024;
    int vals[4], tsum = 0;
    #pragma unroll
    for (int j = 0; j < 4; ++j) {
        int i = base + t * 4 + j;
        vals[j] = (i < n) ? deg[i] : 0;
        tsum += vals[j];
    }
    int lane = t & 63, w = t >> 6;
    int incl = tsum;
    #pragma unroll
    for (int d = 1; d < 64; d <<= 1) { int u = __shfl_up(incl, d, 64); if (lane >= d) incl += u; }
    __shared__ int ws[4];
    if (lane == 63) ws[w] = incl;
    __syncthreads();
    int add = partial[blockIdx.x];
    #pragma unroll
    for (int i = 0; i < 4; ++i) if (i < w) add += ws[i];
    int run = add + incl - tsum;
    #pragma unroll
    for (int j = 0; j < 4; ++j) {
        int i = base + t * 4 + j;
        if (i < n) { offs[i] = run; cursor[i] = run; }
        run += vals[j];
    }
}

// ---------------- destination-partitioned scatter ----------------

__global__ __launch_bounds__(256) void scatter_kernel(const int* __restrict__ row,
                                                      const int* __restrict__ col,
                                                      int* __restrict__ cursor,
                                                      int* __restrict__ csr,
                                                      int e, int n, int bp) {
    int p = blockIdx.x / bp;
    int cblk = blockIdx.x % bp;
    int lo = (int)(((long long)n * p) / SC_P);
    int hi = (int)(((long long)n * (p + 1)) / SC_P);
    int base = cblk * 1024;
    #pragma unroll
    for (int j = 0; j < 4; ++j) {
        int i = base + j * 256 + threadIdx.x;
        if (i < e) {
            int d = col[i];
            if (d >= lo && d < hi) {
                int pos = atomicAdd(&cursor[d], 1);
                csr[pos] = row[i];
            }
        }
    }
}

// ---------------- GEMM: hsb = bf16( (x @ W) * dinv[row] ), MFMA 16x16x32 ----------------

constexpr int MT = 64;
constexpr int XS_STRIDE = 264;   // bf16 elems per LDS row (528B: 16B-aligned, pad vs 512)

__global__ __launch_bounds__(256) void gemm_kernel(const float* __restrict__ x,
                                                   const ushort* __restrict__ Wt,
                                                   const float* __restrict__ dinv,
                                                   ushort* __restrict__ hsb, int n) {
    __shared__ ushort xs[MT * XS_STRIDE];
    __shared__ float sdinv[MT];
    int t = threadIdx.x, lane = t & 63, w = t >> 6;
    int row0 = blockIdx.x * MT;

    bf16x8 bfrag[8][2];
    #pragma unroll
    for (int c = 0; c < 8; ++c)
        #pragma unroll
        for (int f = 0; f < 2; ++f)
            bfrag[c][f] = *(const bf16x8*)(Wt + (size_t)(((c * 8) + (w * 2 + f)) * 64 + lane) * 8);

    {
        int r = t >> 2, q = t & 3;
        int gr = row0 + r; if (gr >= n) gr = n - 1;
        const float* xp = x + (size_t)gr * KDIM + q * 64;
        ushort* dst = xs + r * XS_STRIDE + q * 64;
        #pragma unroll
        for (int i = 0; i < 16; ++i) {
            float4 v = *(const float4*)(xp + i * 4);
            ushort4 o;
            o.x = f2bf(v.x); o.y = f2bf(v.y); o.z = f2bf(v.z); o.w = f2bf(v.w);
            *(ushort4*)(dst + i * 4) = o;
        }
        if (t < MT) { int g = row0 + t; sdinv[t] = dinv[(g < n) ? g : (n - 1)]; }
    }
    __syncthreads();

    #pragma unroll
    for (int s = 0; s < MT / 16; ++s) {
        f32x4 acc0 = {0.f, 0.f, 0.f, 0.f}, acc1 = {0.f, 0.f, 0.f, 0.f};
        #pragma unroll
        for (int c = 0; c < 8; ++c) {
            const ushort* ap = xs + (s * 16 + (lane & 15)) * XS_STRIDE + c * 32 + (lane >> 4) * 8;
            bf16x8 afrag = *(const bf16x8*)ap;
            acc0 = __builtin_amdgcn_mfma_f32_16x16x32_bf16(afrag, bfrag[c][0], acc0, 0, 0, 0);
            acc1 = __builtin_amdgcn_mfma_f32_16x16x32_bf16(afrag, bfrag[c][1], acc1, 0, 0, 0);
        }
        #pragma unroll
        for (int reg = 0; reg < 4; ++reg) {
            int rl = s * 16 + (lane >> 4) * 4 + reg;
            int gr = row0 + rl;
            if (gr < n) {
                float d = sdinv[rl];
                int col0 = w * 32 + (lane & 15);
                hsb[(size_t)gr * HDIM + col0]      = f2bf(acc0[reg] * d);
                hsb[(size_t)gr * HDIM + col0 + 16] = f2bf(acc1[reg] * d);
            }
        }
    }
}

// ---------------- aggregation: wave/node, 4 edge-slots x 16 channel-groups ----------------
// lane = slot*16 + chg; each lane gathers uint4 (8 bf16 channels); 4 edges in
// flight per inner iteration; masked slots gather the zero row at index n.

__global__ __launch_bounds__(256) void aggregate_kernel(
    const ushort* __restrict__ hsb, const int* __restrict__ offs,
    const int* __restrict__ deg, const int* __restrict__ csr,
    const float* __restrict__ dinv, const float* __restrict__ b,
    const float* __restrict__ alpha, float* __restrict__ out, int n) {
    int wv = threadIdx.x >> 6, lane = threadIdx.x & 63;
    int node = blockIdx.x * 4 + wv;
    if (node >= n) return;
    int base = offs[node], cnt = deg[node];
    int slot = lane >> 4, chg = lane & 15;
    const uint4* hs4 = (const uint4*)hsb;   // 16 uint4 per 128-channel row

    float a[8];
    #pragma unroll
    for (int i = 0; i < 8; ++i) a[i] = 0.f;

    if (slot == 0) {                        // self loop
        uint4 u = hs4[(size_t)node * 16 + chg];
        accum8(a, u);
    }

    for (int j = 0; j < cnt; j += 64) {
        int m = min(cnt - j, 64);
        int idx = (lane < m) ? csr[base + j + lane] : n;   // n = zero row
        for (int g = 0; g < m; g += 16) {
            int s0 = __shfl(idx, g + slot, 64);
            int s1 = __shfl(idx, g + 4 + slot, 64);
            int s2 = __shfl(idx, g + 8 + slot, 64);
            int s3 = __shfl(idx, g + 12 + slot, 64);
            uint4 u0 = hs4[(size_t)s0 * 16 + chg];
            uint4 u1 = hs4[(size_t)s1 * 16 + chg];
            uint4 u2 = hs4[(size_t)s2 * 16 + chg];
            uint4 u3 = hs4[(size_t)s3 * 16 + chg];
            accum8(a, u0); accum8(a, u1); accum8(a, u2); accum8(a, u3);
        }
    }

    // reduce across the 4 edge-slots (lane bits 4,5)
    #pragma unroll
    for (int i = 0; i < 8; ++i) {
        a[i] += __shfl_xor(a[i], 16, 64);
        a[i] += __shfl_xor(a[i], 32, 64);
    }

    if (slot == 0) {                        // 16 lanes write contiguous 512B row
        float dc = dinv[node];
        int c0 = chg * 8;
        float o[8];
        #pragma unroll
        for (int i = 0; i < 8; ++i) {
            float v = fmaf(dc, a[i], b[c0 + i]);
            o[i] = v >= 0.f ? v : alpha[c0 + i] * v;
        }
        float* op = out + (size_t)node * HDIM + c0;
        *(float4*)op       = make_float4(o[0], o[1], o[2], o[3]);
        *(float4*)(op + 4) = make_float4(o[4], o[5], o[6], o[7]);
    }
}

// ---------------- launch ----------------

extern "C" void kernel_launch(void* const* d_in, const int* in_sizes, int n_in,
                              void* d_out, int out_size, void* d_ws, size_t ws_size,
                              hipStream_t stream) {
    const float* x     = (const float*)d_in[0];
    const int*   ei    = (const int*)d_in[1];
    const float* W     = (const float*)d_in[2];
    const float* b     = (const float*)d_in[3];
    const float* alpha = (const float*)d_in[4];
    float* out = (float*)d_out;

    int E = in_sizes[1] / 2;
    int N = in_sizes[0] / KDIM;

    // workspace: hsb bf16[(N+1)*128] | Wt bf16[32768] | dinv f32[N] | deg/offs/cursor int[N] | partial[512] | csr[E]
    ushort* hsb = (ushort*)d_ws;
    ushort* Wt  = hsb + (size_t)(N + 1) * HDIM;
    float* dinv = (float*)(Wt + 32768);
    int* deg    = (int*)(dinv + N);
    int* offs   = deg + N;
    int* cursor = offs + N;
    int* partial = cursor + N;
    int* csr    = partial + 512;

    const int* rowp = ei;      // sources
    const int* colp = ei + E;  // destinations

    int nb = (N + 1023) / 1024;
    int bp = (E + 1023) / 1024;

    hipLaunchKernelGGL(prep_kernel,      dim3(17 + (N + 255) / 256), dim3(256), 0, stream, W, Wt, hsb, deg, N);
    hipLaunchKernelGGL(count_deg_kernel, dim3((E + 255) / 256), dim3(256), 0, stream, colp, deg, E);
    hipLaunchKernelGGL(scanA_kernel,     dim3(nb), dim3(256), 0, stream, deg, dinv, partial, N);
    hipLaunchKernelGGL(scanB_kernel,     dim3(1),  dim3(256), 0, stream, partial, nb);
    hipLaunchKernelGGL(scanC_kernel,     dim3(nb), dim3(256), 0, stream, deg, partial, offs, cursor, N);
    hipLaunchKernelGGL(scatter_kernel,   dim3(SC_P * bp), dim3(256), 0, stream, rowp, colp, cursor, csr, E, N, bp);
    hipLaunchKernelGGL(gemm_kernel,      dim3((N + MT - 1) / MT), dim3(256), 0, stream, x, Wt, dinv, hsb, N);
    hipLaunchKernelGGL(aggregate_kernel, dim3((N + 3) / 4), dim3(256), 0, stream,
                       hsb, offs, deg, csr, dinv, b, alpha, out, N);
}

// Round 4
// 366.126 us; speedup vs baseline: 1.7138x; 1.1915x over previous
//
#include <hip/hip_runtime.h>

constexpr int KDIM = 256;   // input feature dim
constexpr int HDIM = 128;   // output feature dim
constexpr int GB   = 128;   // coarse-pass blocks
constexpr int BK   = 128;   // nodes per coarse bucket (col>>7)

typedef __bf16 bf16x8 __attribute__((ext_vector_type(8)));
typedef float  f32x4  __attribute__((ext_vector_type(4)));

__device__ __forceinline__ ushort f2bf(float f) {
    unsigned u = __float_as_uint(f);
    unsigned r = (u + 0x7fffu + ((u >> 16) & 1u)) >> 16;   // RNE
    return (ushort)r;
}

__device__ __forceinline__ void accum8(float* a, uint4 u) {
    a[0] += __uint_as_float(u.x << 16); a[1] += __uint_as_float(u.x & 0xffff0000u);
    a[2] += __uint_as_float(u.y << 16); a[3] += __uint_as_float(u.y & 0xffff0000u);
    a[4] += __uint_as_float(u.z << 16); a[5] += __uint_as_float(u.z & 0xffff0000u);
    a[6] += __uint_as_float(u.w << 16); a[7] += __uint_as_float(u.w & 0xffff0000u);
}

// ---------------- prep: Wt in B-fragment layout (bf16) + zero gather row ----------------
__global__ __launch_bounds__(256) void prep_kernel(const float* __restrict__ W,
                                                   ushort* __restrict__ Wt,
                                                   ushort* __restrict__ hsb, int n) {
    int b = blockIdx.x, t = threadIdx.x;
    if (b < 16) {
        int g = b * 256 + t;            // [0, 4096)
        int lane = g & 63, cn = g >> 6; // cn = c*8+nf
        int c = cn >> 3, nf = cn & 7;
        int ncol = nf * 16 + (lane & 15);
        int k0 = c * 32 + (lane >> 4) * 8;
        ushort* dst = Wt + (size_t)g * 8;
        #pragma unroll
        for (int j = 0; j < 8; ++j) dst[j] = f2bf(W[(k0 + j) * HDIM + ncol]);
    } else {
        if (t < HDIM) hsb[(size_t)n * HDIM + t] = 0;   // zero row for masked gathers
    }
}

// ---------------- C1: coarse bucket histogram (LDS atomics only) ----------------
__global__ __launch_bounds__(256) void c1_count_kernel(const int* __restrict__ col,
                                                       int* __restrict__ histG,
                                                       int e, int nb, int chunk) {
    extern __shared__ int hist[];           // nb ints
    int g = blockIdx.x, t = threadIdx.x;
    for (int i = t; i < nb; i += 256) hist[i] = 0;
    __syncthreads();
    int lo = g * chunk, hi = min(lo + chunk, e);
    for (int i = lo + t; i < hi; i += 256)
        atomicAdd(&hist[col[i] >> 7], 1);
    __syncthreads();
    for (int i = t; i < nb; i += 256) histG[i * GB + g] = hist[i];
}

// ---------------- hierarchical scan (generic) ----------------
__global__ __launch_bounds__(256) void scanA_kernel(const int* __restrict__ in,
                                                    int* __restrict__ partial, int n) {
    int t = threadIdx.x, base = blockIdx.x * 1024;
    int s = 0;
    #pragma unroll
    for (int j = 0; j < 4; ++j) {
        int i = base + j * 256 + t;
        if (i < n) s += in[i];
    }
    __shared__ int ws[4];
    #pragma unroll
    for (int d = 1; d < 64; d <<= 1) s += __shfl_xor(s, d, 64);
    int lane = t & 63, w = t >> 6;
    if (lane == 0) ws[w] = s;
    __syncthreads();
    if (t == 0) partial[blockIdx.x] = ws[0] + ws[1] + ws[2] + ws[3];
}

__global__ void scanB_kernel(int* __restrict__ partial, int nb) {  // nb <= 256, 1 block
    int t = threadIdx.x;
    int v = (t < nb) ? partial[t] : 0;
    int orig = v;
    int lane = t & 63, w = t >> 6;
    #pragma unroll
    for (int d = 1; d < 64; d <<= 1) { int u = __shfl_up(v, d, 64); if (lane >= d) v += u; }
    __shared__ int ws[4];
    if (lane == 63) ws[w] = v;
    __syncthreads();
    int add = 0;
    #pragma unroll
    for (int i = 0; i < 4; ++i) if (i < w) add += ws[i];
    if (t < nb) partial[t] = v + add - orig;   // exclusive
}

__global__ __launch_bounds__(256) void scanC_kernel(const int* __restrict__ in,
                                                    const int* __restrict__ partial,
                                                    int* __restrict__ out, int n) {
    int t = threadIdx.x, base = blockIdx.x * 1024;
    int vals[4], tsum = 0;
    #pragma unroll
    for (int j = 0; j < 4; ++j) {
        int i = base + t * 4 + j;
        vals[j] = (i < n) ? in[i] : 0;
        tsum += vals[j];
    }
    int lane = t & 63, w = t >> 6;
    int incl = tsum;
    #pragma unroll
    for (int d = 1; d < 64; d <<= 1) { int u = __shfl_up(incl, d, 64); if (lane >= d) incl += u; }
    __shared__ int ws[4];
    if (lane == 63) ws[w] = incl;
    __syncthreads();
    int add = partial[blockIdx.x];
    #pragma unroll
    for (int i = 0; i < 4; ++i) if (i < w) add += ws[i];
    int run = add + incl - tsum;
    #pragma unroll
    for (int j = 0; j < 4; ++j) {
        int i = base + t * 4 + j;
        if (i < n) out[i] = run;
        run += vals[j];
    }
}

// ---------------- C3: coarse place (LDS cursors, packed (row<<7)|loc) ----------------
__global__ __launch_bounds__(256) void c3_place_kernel(const int* __restrict__ row,
                                                       const int* __restrict__ col,
                                                       const int* __restrict__ histS,
                                                       uint* __restrict__ ebuf,
                                                       int e, int nb, int chunk) {
    extern __shared__ int cur[];            // nb ints
    int g = blockIdx.x, t = threadIdx.x;
    for (int i = t; i < nb; i += 256) cur[i] = histS[i * GB + g];
    __syncthreads();
    int lo = g * chunk, hi = min(lo + chunk, e);
    for (int i = lo + t; i < hi; i += 256) {
        int c = col[i];
        int b = c >> 7;
        int pos = atomicAdd(&cur[b], 1);
        ebuf[pos] = ((uint)row[i] << 7) | (uint)(c & 127);
    }
}

// ---------------- F: fine counting sort per bucket + deg/offs/dinv ----------------
__global__ __launch_bounds__(256) void fine_kernel(const int* __restrict__ histS,
                                                   uint* __restrict__ ebuf,   // in-place -> csr
                                                   int* __restrict__ deg,
                                                   int* __restrict__ offs,
                                                   float* __restrict__ dinv,
                                                   int e, int nb, int n) {
    __shared__ uint elist[4096];
    __shared__ uint csrl[4096];
    __shared__ int hist[BK], excl[BK], cur[BK];
    int b = blockIdx.x, t = threadIdx.x;
    int seg0 = histS[b * GB];
    int seg1 = (b + 1 < nb) ? histS[(b + 1) * GB] : e;
    int cnt = min(seg1 - seg0, 4096);

    if (t < BK) { hist[t] = 0; cur[t] = 0; }
    __syncthreads();
    for (int i = t; i < cnt; i += 256) {
        uint v = ebuf[seg0 + i];
        elist[i] = v;
        atomicAdd(&hist[v & 127], 1);
    }
    __syncthreads();
    if (t < 64) {                       // exclusive scan of 128 bins, wave 0
        int v0 = hist[2 * t], v1 = hist[2 * t + 1];
        int s = v0 + v1, incl = s;
        #pragma unroll
        for (int d = 1; d < 64; d <<= 1) { int u = __shfl_up(incl, d, 64); if (t >= d) incl += u; }
        int base = incl - s;
        excl[2 * t] = base; excl[2 * t + 1] = base + v0;
    }
    __syncthreads();
    for (int i = t; i < cnt; i += 256) {
        uint v = elist[i];
        int d = v & 127;
        int r = atomicAdd(&cur[d], 1);
        csrl[excl[d] + r] = v >> 7;
    }
    __syncthreads();
    for (int i = t; i < cnt; i += 256) ebuf[seg0 + i] = csrl[i];   // csr, coalesced
    if (t < BK) {
        int node = b * BK + t;
        if (node < n) {
            int dg = hist[t];
            deg[node]  = dg;
            offs[node] = seg0 + excl[t];
            dinv[node] = rsqrtf((float)(dg + 1));
        }
    }
}

// ---------------- GEMM: hsb = bf16( (x @ W) * dinv[row] ), MFMA 16x16x32 ----------------

constexpr int MT = 64;
constexpr int XS_STRIDE = 264;

__global__ __launch_bounds__(256) void gemm_kernel(const float* __restrict__ x,
                                                   const ushort* __restrict__ Wt,
                                                   const float* __restrict__ dinv,
                                                   ushort* __restrict__ hsb, int n) {
    __shared__ ushort xs[MT * XS_STRIDE];
    __shared__ float sdinv[MT];
    int t = threadIdx.x, lane = t & 63, w = t >> 6;
    int row0 = blockIdx.x * MT;

    bf16x8 bfrag[8][2];
    #pragma unroll
    for (int c = 0; c < 8; ++c)
        #pragma unroll
        for (int f = 0; f < 2; ++f)
            bfrag[c][f] = *(const bf16x8*)(Wt + (size_t)(((c * 8) + (w * 2 + f)) * 64 + lane) * 8);

    {
        int r = t >> 2, q = t & 3;
        int gr = row0 + r; if (gr >= n) gr = n - 1;
        const float* xp = x + (size_t)gr * KDIM + q * 64;
        ushort* dst = xs + r * XS_STRIDE + q * 64;
        #pragma unroll
        for (int i = 0; i < 16; ++i) {
            float4 v = *(const float4*)(xp + i * 4);
            ushort4 o;
            o.x = f2bf(v.x); o.y = f2bf(v.y); o.z = f2bf(v.z); o.w = f2bf(v.w);
            *(ushort4*)(dst + i * 4) = o;
        }
        if (t < MT) { int g = row0 + t; sdinv[t] = dinv[(g < n) ? g : (n - 1)]; }
    }
    __syncthreads();

    #pragma unroll
    for (int s = 0; s < MT / 16; ++s) {
        f32x4 acc0 = {0.f, 0.f, 0.f, 0.f}, acc1 = {0.f, 0.f, 0.f, 0.f};
        #pragma unroll
        for (int c = 0; c < 8; ++c) {
            const ushort* ap = xs + (s * 16 + (lane & 15)) * XS_STRIDE + c * 32 + (lane >> 4) * 8;
            bf16x8 afrag = *(const bf16x8*)ap;
            acc0 = __builtin_amdgcn_mfma_f32_16x16x32_bf16(afrag, bfrag[c][0], acc0, 0, 0, 0);
            acc1 = __builtin_amdgcn_mfma_f32_16x16x32_bf16(afrag, bfrag[c][1], acc1, 0, 0, 0);
        }
        #pragma unroll
        for (int reg = 0; reg < 4; ++reg) {
            int rl = s * 16 + (lane >> 4) * 4 + reg;
            int gr = row0 + rl;
            if (gr < n) {
                float d = sdinv[rl];
                int col0 = w * 32 + (lane & 15);
                hsb[(size_t)gr * HDIM + col0]      = f2bf(acc0[reg] * d);
                hsb[(size_t)gr * HDIM + col0 + 16] = f2bf(acc1[reg] * d);
            }
        }
    }
}

// ---------------- aggregation: wave/node, 4 edge-slots x 16 channel-groups ----------------

__global__ __launch_bounds__(256) void aggregate_kernel(
    const ushort* __restrict__ hsb, const int* __restrict__ offs,
    const int* __restrict__ deg, const int* __restrict__ csr,
    const float* __restrict__ dinv, const float* __restrict__ b,
    const float* __restrict__ alpha, float* __restrict__ out, int n) {
    int wv = threadIdx.x >> 6, lane = threadIdx.x & 63;
    int node = blockIdx.x * 4 + wv;
    if (node >= n) return;
    int base = offs[node], cnt = deg[node];
    int slot = lane >> 4, chg = lane & 15;
    const uint4* hs4 = (const uint4*)hsb;

    float a[8];
    #pragma unroll
    for (int i = 0; i < 8; ++i) a[i] = 0.f;

    if (slot == 0) {                        // self loop
        uint4 u = hs4[(size_t)node * 16 + chg];
        accum8(a, u);
    }

    for (int j = 0; j < cnt; j += 64) {
        int m = min(cnt - j, 64);
        int idx = (lane < m) ? csr[base + j + lane] : n;   // n = zero row
        for (int g = 0; g < m; g += 16) {
            int s0 = __shfl(idx, g + slot, 64);
            int s1 = __shfl(idx, g + 4 + slot, 64);
            int s2 = __shfl(idx, g + 8 + slot, 64);
            int s3 = __shfl(idx, g + 12 + slot, 64);
            uint4 u0 = hs4[(size_t)s0 * 16 + chg];
            uint4 u1 = hs4[(size_t)s1 * 16 + chg];
            uint4 u2 = hs4[(size_t)s2 * 16 + chg];
            uint4 u3 = hs4[(size_t)s3 * 16 + chg];
            accum8(a, u0); accum8(a, u1); accum8(a, u2); accum8(a, u3);
        }
    }

    #pragma unroll
    for (int i = 0; i < 8; ++i) {
        a[i] += __shfl_xor(a[i], 16, 64);
        a[i] += __shfl_xor(a[i], 32, 64);
    }

    if (slot == 0) {
        float dc = dinv[node];
        int c0 = chg * 8;
        float o[8];
        #pragma unroll
        for (int i = 0; i < 8; ++i) {
            float v = fmaf(dc, a[i], b[c0 + i]);
            o[i] = v >= 0.f ? v : alpha[c0 + i] * v;
        }
        float* op = out + (size_t)node * HDIM + c0;
        *(float4*)op       = make_float4(o[0], o[1], o[2], o[3]);
        *(float4*)(op + 4) = make_float4(o[4], o[5], o[6], o[7]);
    }
}

// ---------------- launch ----------------

extern "C" void kernel_launch(void* const* d_in, const int* in_sizes, int n_in,
                              void* d_out, int out_size, void* d_ws, size_t ws_size,
                              hipStream_t stream) {
    const float* x     = (const float*)d_in[0];
    const int*   ei    = (const int*)d_in[1];
    const float* W     = (const float*)d_in[2];
    const float* b     = (const float*)d_in[3];
    const float* alpha = (const float*)d_in[4];
    float* out = (float*)d_out;

    int E = in_sizes[1] / 2;
    int N = in_sizes[0] / KDIM;
    int NB = (N + BK - 1) / BK;          // coarse buckets
    int SCAN_N = NB * GB;
    int chunk = (E + GB - 1) / GB;

    // ws: hsb bf16[(N+1)*128] | Wt bf16[32768] | dinv f32[N] | degG int[SCAN_N] (deg aliases)
    //   | offs int[N] | histS int[SCAN_N] | partial int[512] | ebuf/csr uint[E] (aliased)
    ushort* hsb  = (ushort*)d_ws;
    ushort* Wt   = hsb + (size_t)(N + 1) * HDIM;
    float* dinv  = (float*)(Wt + 32768);
    int* degG    = (int*)(dinv + N);     // C1 histogram, later per-node deg
    int* offs    = degG + SCAN_N;
    int* histS   = offs + N;
    int* partial = histS + SCAN_N;
    uint* ebuf   = (uint*)(partial + 512);   // becomes csr in fine_kernel

    const int* rowp = ei;      // sources
    const int* colp = ei + E;  // destinations

    int nbScan = (SCAN_N + 1023) / 1024;
    size_t ldsNB = (size_t)NB * sizeof(int);

    hipLaunchKernelGGL(prep_kernel,  dim3(17), dim3(256), 0, stream, W, Wt, hsb, N);
    hipLaunchKernelGGL(c1_count_kernel, dim3(GB), dim3(256), ldsNB, stream, colp, degG, E, NB, chunk);
    hipLaunchKernelGGL(scanA_kernel, dim3(nbScan), dim3(256), 0, stream, degG, partial, SCAN_N);
    hipLaunchKernelGGL(scanB_kernel, dim3(1), dim3(256), 0, stream, partial, nbScan);
    hipLaunchKernelGGL(scanC_kernel, dim3(nbScan), dim3(256), 0, stream, degG, partial, histS, SCAN_N);
    hipLaunchKernelGGL(c3_place_kernel, dim3(GB), dim3(256), ldsNB, stream, rowp, colp, histS, ebuf, E, NB, chunk);
    hipLaunchKernelGGL(fine_kernel,  dim3(NB), dim3(256), 0, stream, histS, ebuf, degG, offs, dinv, E, NB, N);
    hipLaunchKernelGGL(gemm_kernel,  dim3((N + MT - 1) / MT), dim3(256), 0, stream, x, Wt, dinv, hsb, N);
    hipLaunchKernelGGL(aggregate_kernel, dim3((N + 3) / 4), dim3(256), 0, stream,
                       hsb, offs, degG, (const int*)ebuf, dinv, b, alpha, out, N);
}

// Round 5
// 338.281 us; speedup vs baseline: 1.8549x; 1.0823x over previous
//
#include <hip/hip_runtime.h>

constexpr int KDIM = 256;   // input feature dim
constexpr int HDIM = 128;   // output feature dim
constexpr int GB   = 256;   // coarse-pass blocks
constexpr int BK   = 128;   // nodes per coarse bucket (col>>7)

typedef __bf16 bf16x8 __attribute__((ext_vector_type(8)));
typedef float  f32x4  __attribute__((ext_vector_type(4)));

__device__ __forceinline__ ushort f2bf(float f) {
    unsigned u = __float_as_uint(f);
    unsigned r = (u + 0x7fffu + ((u >> 16) & 1u)) >> 16;   // RNE
    return (ushort)r;
}

__device__ __forceinline__ void accum8(float* a, uint4 u) {
    a[0] += __uint_as_float(u.x << 16); a[1] += __uint_as_float(u.x & 0xffff0000u);
    a[2] += __uint_as_float(u.y << 16); a[3] += __uint_as_float(u.y & 0xffff0000u);
    a[4] += __uint_as_float(u.z << 16); a[5] += __uint_as_float(u.z & 0xffff0000u);
    a[6] += __uint_as_float(u.w << 16); a[7] += __uint_as_float(u.w & 0xffff0000u);
}

// ---------------- fused: prep (blocks 0..16) + C1 coarse histogram (blocks 17..) ----
// Wt frag layout: g = (c*8 + nf)*64 + lane holds 8 contiguous-k bf16:
//   k = c*32 + (lane>>4)*8 + j,  n = nf*16 + (lane&15)
__global__ __launch_bounds__(256) void prep_c1_kernel(const float* __restrict__ W,
                                                      ushort* __restrict__ Wt,
                                                      ushort* __restrict__ hsb,
                                                      const int* __restrict__ col,
                                                      int* __restrict__ histG,
                                                      int n, int e, int nb, int chunk) {
    extern __shared__ int hist[];           // nb ints (c1 part only)
    int b = blockIdx.x, t = threadIdx.x;
    if (b < 16) {
        int g = b * 256 + t;            // [0, 4096)
        int lane = g & 63, cn = g >> 6; // cn = c*8+nf
        int c = cn >> 3, nf = cn & 7;
        int ncol = nf * 16 + (lane & 15);
        int k0 = c * 32 + (lane >> 4) * 8;
        ushort* dst = Wt + (size_t)g * 8;
        #pragma unroll
        for (int j = 0; j < 8; ++j) dst[j] = f2bf(W[(k0 + j) * HDIM + ncol]);
        return;
    }
    if (b == 16) {
        if (t < HDIM) hsb[(size_t)n * HDIM + t] = 0;   // zero row for masked gathers
        return;
    }
    int g = b - 17;                         // c1 block id, [0, GB)
    for (int i = t; i < nb; i += 256) hist[i] = 0;
    __syncthreads();
    int lo = g * chunk, hi = min(lo + chunk, e);
    for (int i = lo + t; i < hi; i += 256)
        atomicAdd(&hist[col[i] >> 7], 1);
    __syncthreads();
    for (int i = t; i < nb; i += 256) histG[i * GB + g] = hist[i];
}

// ---------------- hierarchical scan (generic) ----------------
__global__ __launch_bounds__(256) void scanA_kernel(const int* __restrict__ in,
                                                    int* __restrict__ partial, int n) {
    int t = threadIdx.x, base = blockIdx.x * 1024;
    int s = 0;
    #pragma unroll
    for (int j = 0; j < 4; ++j) {
        int i = base + j * 256 + t;
        if (i < n) s += in[i];
    }
    __shared__ int ws[4];
    #pragma unroll
    for (int d = 1; d < 64; d <<= 1) s += __shfl_xor(s, d, 64);
    int lane = t & 63, w = t >> 6;
    if (lane == 0) ws[w] = s;
    __syncthreads();
    if (t == 0) partial[blockIdx.x] = ws[0] + ws[1] + ws[2] + ws[3];
}

__global__ void scanB_kernel(int* __restrict__ partial, int nb) {  // nb <= 256, 1 block
    int t = threadIdx.x;
    int v = (t < nb) ? partial[t] : 0;
    int orig = v;
    int lane = t & 63, w = t >> 6;
    #pragma unroll
    for (int d = 1; d < 64; d <<= 1) { int u = __shfl_up(v, d, 64); if (lane >= d) v += u; }
    __shared__ int ws[4];
    if (lane == 63) ws[w] = v;
    __syncthreads();
    int add = 0;
    #pragma unroll
    for (int i = 0; i < 4; ++i) if (i < w) add += ws[i];
    if (t < nb) partial[t] = v + add - orig;   // exclusive
}

__global__ __launch_bounds__(256) void scanC_kernel(const int* __restrict__ in,
                                                    const int* __restrict__ partial,
                                                    int* __restrict__ out, int n) {
    int t = threadIdx.x, base = blockIdx.x * 1024;
    int vals[4], tsum = 0;
    #pragma unroll
    for (int j = 0; j < 4; ++j) {
        int i = base + t * 4 + j;
        vals[j] = (i < n) ? in[i] : 0;
        tsum += vals[j];
    }
    int lane = t & 63, w = t >> 6;
    int incl = tsum;
    #pragma unroll
    for (int d = 1; d < 64; d <<= 1) { int u = __shfl_up(incl, d, 64); if (lane >= d) incl += u; }
    __shared__ int ws[4];
    if (lane == 63) ws[w] = incl;
    __syncthreads();
    int add = partial[blockIdx.x];
    #pragma unroll
    for (int i = 0; i < 4; ++i) if (i < w) add += ws[i];
    int run = add + incl - tsum;
    #pragma unroll
    for (int j = 0; j < 4; ++j) {
        int i = base + t * 4 + j;
        if (i < n) out[i] = run;
        run += vals[j];
    }
}

// ---------------- C3: coarse place (LDS cursors, packed (row<<7)|loc) ----------------
__global__ __launch_bounds__(256) void c3_place_kernel(const int* __restrict__ row,
                                                       const int* __restrict__ col,
                                                       const int* __restrict__ histS,
                                                       uint* __restrict__ ebuf,
                                                       int e, int nb, int chunk) {
    extern __shared__ int cur[];            // nb ints
    int g = blockIdx.x, t = threadIdx.x;
    for (int i = t; i < nb; i += 256) cur[i] = histS[i * GB + g];
    __syncthreads();
    int lo = g * chunk, hi = min(lo + chunk, e);
    for (int i = lo + t; i < hi; i += 256) {
        int c = col[i];
        int b = c >> 7;
        int pos = atomicAdd(&cur[b], 1);
        ebuf[pos] = ((uint)row[i] << 7) | (uint)(c & 127);
    }
}

// ---------------- F: fine counting sort per bucket + deg/offs/dinv ----------------
__global__ __launch_bounds__(256) void fine_kernel(const int* __restrict__ histS,
                                                   uint* __restrict__ ebuf,   // in-place -> csr
                                                   int* __restrict__ deg,
                                                   int* __restrict__ offs,
                                                   float* __restrict__ dinv,
                                                   int e, int nb, int n) {
    __shared__ uint elist[4096];
    __shared__ uint csrl[4096];
    __shared__ int hist[BK], excl[BK], cur[BK];
    int b = blockIdx.x, t = threadIdx.x;
    int seg0 = histS[b * GB];
    int seg1 = (b + 1 < nb) ? histS[(b + 1) * GB] : e;
    int cnt = min(seg1 - seg0, 4096);

    if (t < BK) { hist[t] = 0; cur[t] = 0; }
    __syncthreads();
    for (int i = t; i < cnt; i += 256) {
        uint v = ebuf[seg0 + i];
        elist[i] = v;
        atomicAdd(&hist[v & 127], 1);
    }
    __syncthreads();
    if (t < 64) {                       // exclusive scan of 128 bins, wave 0
        int v0 = hist[2 * t], v1 = hist[2 * t + 1];
        int s = v0 + v1, incl = s;
        #pragma unroll
        for (int d = 1; d < 64; d <<= 1) { int u = __shfl_up(incl, d, 64); if (t >= d) incl += u; }
        int base = incl - s;
        excl[2 * t] = base; excl[2 * t + 1] = base + v0;
    }
    __syncthreads();
    for (int i = t; i < cnt; i += 256) {
        uint v = elist[i];
        int d = v & 127;
        int r = atomicAdd(&cur[d], 1);
        csrl[excl[d] + r] = v >> 7;
    }
    __syncthreads();
    for (int i = t; i < cnt; i += 256) ebuf[seg0 + i] = csrl[i];   // csr, coalesced
    if (t < BK) {
        int node = b * BK + t;
        if (node < n) {
            int dg = hist[t];
            deg[node]  = dg;
            offs[node] = seg0 + excl[t];
            dinv[node] = rsqrtf((float)(dg + 1));
        }
    }
}

// ---------------- GEMM: hsb = bf16( (x @ W) * dinv[row] ), MFMA 16x16x32 ----------------
// Staging: wave w stages rows [w*16, w*16+16); per row, 64 lanes read the full
// 1KB row contiguously (each touched 64B line fully consumed by its instruction).

constexpr int MT = 64;
constexpr int XS_STRIDE = 264;

__global__ __launch_bounds__(256) void gemm_kernel(const float* __restrict__ x,
                                                   const ushort* __restrict__ Wt,
                                                   const float* __restrict__ dinv,
                                                   ushort* __restrict__ hsb, int n) {
    __shared__ ushort xs[MT * XS_STRIDE];
    __shared__ float sdinv[MT];
    int t = threadIdx.x, lane = t & 63, w = t >> 6;
    int row0 = blockIdx.x * MT;

    bf16x8 bfrag[8][2];
    #pragma unroll
    for (int c = 0; c < 8; ++c)
        #pragma unroll
        for (int f = 0; f < 2; ++f)
            bfrag[c][f] = *(const bf16x8*)(Wt + (size_t)(((c * 8) + (w * 2 + f)) * 64 + lane) * 8);

    #pragma unroll
    for (int i = 0; i < 16; ++i) {
        int rl = w * 16 + i;
        int gr = row0 + rl; if (gr >= n) gr = n - 1;
        float4 v = *(const float4*)(x + (size_t)gr * KDIM + lane * 4);
        ushort4 o;
        o.x = f2bf(v.x); o.y = f2bf(v.y); o.z = f2bf(v.z); o.w = f2bf(v.w);
        *(ushort4*)(xs + rl * XS_STRIDE + lane * 4) = o;
    }
    if (t < MT) { int g = row0 + t; sdinv[t] = dinv[(g < n) ? g : (n - 1)]; }
    __syncthreads();

    #pragma unroll
    for (int s = 0; s < MT / 16; ++s) {
        f32x4 acc0 = {0.f, 0.f, 0.f, 0.f}, acc1 = {0.f, 0.f, 0.f, 0.f};
        #pragma unroll
        for (int c = 0; c < 8; ++c) {
            const ushort* ap = xs + (s * 16 + (lane & 15)) * XS_STRIDE + c * 32 + (lane >> 4) * 8;
            bf16x8 afrag = *(const bf16x8*)ap;
            acc0 = __builtin_amdgcn_mfma_f32_16x16x32_bf16(afrag, bfrag[c][0], acc0, 0, 0, 0);
            acc1 = __builtin_amdgcn_mfma_f32_16x16x32_bf16(afrag, bfrag[c][1], acc1, 0, 0, 0);
        }
        #pragma unroll
        for (int reg = 0; reg < 4; ++reg) {
            int rl = s * 16 + (lane >> 4) * 4 + reg;
            int gr = row0 + rl;
            if (gr < n) {
                float d = sdinv[rl];
                int col0 = w * 32 + (lane & 15);
                hsb[(size_t)gr * HDIM + col0]      = f2bf(acc0[reg] * d);
                hsb[(size_t)gr * HDIM + col0 + 16] = f2bf(acc1[reg] * d);
            }
        }
    }
}

// ---------------- aggregation: wave/node, 4 edge-slots x 16 channel-groups ----------------

__global__ __launch_bounds__(256) void aggregate_kernel(
    const ushort* __restrict__ hsb, const int* __restrict__ offs,
    const int* __restrict__ deg, const int* __restrict__ csr,
    const float* __restrict__ dinv, const float* __restrict__ b,
    const float* __restrict__ alpha, float* __restrict__ out, int n) {
    int wv = threadIdx.x >> 6, lane = threadIdx.x & 63;
    int node = blockIdx.x * 4 + wv;
    if (node >= n) return;
    int base = offs[node], cnt = deg[node];
    int slot = lane >> 4, chg = lane & 15;
    const uint4* hs4 = (const uint4*)hsb;

    float a[8];
    #pragma unroll
    for (int i = 0; i < 8; ++i) a[i] = 0.f;

    if (slot == 0) {                        // self loop
        uint4 u = hs4[(size_t)node * 16 + chg];
        accum8(a, u);
    }

    for (int j = 0; j < cnt; j += 64) {
        int m = min(cnt - j, 64);
        int idx = (lane < m) ? csr[base + j + lane] : n;   // n = zero row
        for (int g = 0; g < m; g += 16) {
            int s0 = __shfl(idx, g + slot, 64);
            int s1 = __shfl(idx, g + 4 + slot, 64);
            int s2 = __shfl(idx, g + 8 + slot, 64);
            int s3 = __shfl(idx, g + 12 + slot, 64);
            uint4 u0 = hs4[(size_t)s0 * 16 + chg];
            uint4 u1 = hs4[(size_t)s1 * 16 + chg];
            uint4 u2 = hs4[(size_t)s2 * 16 + chg];
            uint4 u3 = hs4[(size_t)s3 * 16 + chg];
            accum8(a, u0); accum8(a, u1); accum8(a, u2); accum8(a, u3);
        }
    }

    #pragma unroll
    for (int i = 0; i < 8; ++i) {
        a[i] += __shfl_xor(a[i], 16, 64);
        a[i] += __shfl_xor(a[i], 32, 64);
    }

    if (slot == 0) {
        float dc = dinv[node];
        int c0 = chg * 8;
        float o[8];
        #pragma unroll
        for (int i = 0; i < 8; ++i) {
            float v = fmaf(dc, a[i], b[c0 + i]);
            o[i] = v >= 0.f ? v : alpha[c0 + i] * v;
        }
        float* op = out + (size_t)node * HDIM + c0;
        *(float4*)op       = make_float4(o[0], o[1], o[2], o[3]);
        *(float4*)(op + 4) = make_float4(o[4], o[5], o[6], o[7]);
    }
}

// ---------------- launch ----------------

extern "C" void kernel_launch(void* const* d_in, const int* in_sizes, int n_in,
                              void* d_out, int out_size, void* d_ws, size_t ws_size,
                              hipStream_t stream) {
    const float* x     = (const float*)d_in[0];
    const int*   ei    = (const int*)d_in[1];
    const float* W     = (const float*)d_in[2];
    const float* b     = (const float*)d_in[3];
    const float* alpha = (const float*)d_in[4];
    float* out = (float*)d_out;

    int E = in_sizes[1] / 2;
    int N = in_sizes[0] / KDIM;
    int NB = (N + BK - 1) / BK;          // coarse buckets
    int SCAN_N = NB * GB;
    int chunk = (E + GB - 1) / GB;

    // ws: hsb bf16[(N+1)*128] | Wt bf16[32768] | dinv f32[N] | degG int[SCAN_N]
    //   | offs int[N] | histS int[SCAN_N] | partial int[512] | ebuf/csr uint[E]
    ushort* hsb  = (ushort*)d_ws;
    ushort* Wt   = hsb + (size_t)(N + 1) * HDIM;
    float* dinv  = (float*)(Wt + 32768);
    int* degG    = (int*)(dinv + N);     // C1 histogram, later per-node deg
    int* offs    = degG + SCAN_N;
    int* histS   = offs + N;
    int* partial = histS + SCAN_N;
    uint* ebuf   = (uint*)(partial + 512);   // becomes csr in fine_kernel

    const int* rowp = ei;      // sources
    const int* colp = ei + E;  // destinations

    int nbScan = (SCAN_N + 1023) / 1024;
    size_t ldsNB = (size_t)NB * sizeof(int);

    hipLaunchKernelGGL(prep_c1_kernel, dim3(17 + GB), dim3(256), ldsNB, stream,
                       W, Wt, hsb, colp, degG, N, E, NB, chunk);
    hipLaunchKernelGGL(scanA_kernel, dim3(nbScan), dim3(256), 0, stream, degG, partial, SCAN_N);
    hipLaunchKernelGGL(scanB_kernel, dim3(1), dim3(256), 0, stream, partial, nbScan);
    hipLaunchKernelGGL(scanC_kernel, dim3(nbScan), dim3(256), 0, stream, degG, partial, histS, SCAN_N);
    hipLaunchKernelGGL(c3_place_kernel, dim3(GB), dim3(256), ldsNB, stream, rowp, colp, histS, ebuf, E, NB, chunk);
    hipLaunchKernelGGL(fine_kernel,  dim3(NB), dim3(256), 0, stream, histS, ebuf, degG, offs, dinv, E, NB, N);
    hipLaunchKernelGGL(gemm_kernel,  dim3((N + MT - 1) / MT), dim3(256), 0, stream, x, Wt, dinv, hsb, N);
    hipLaunchKernelGGL(aggregate_kernel, dim3((N + 3) / 4), dim3(256), 0, stream,
                       hsb, offs, degG, (const int*)ebuf, dinv, b, alpha, out, N);
}

// Round 6
// 334.019 us; speedup vs baseline: 1.8786x; 1.0128x over previous
//
#include <hip/hip_runtime.h>

constexpr int KDIM  = 256;   // input feature dim
constexpr int HDIM  = 128;   // output feature dim
constexpr int BK    = 128;   // nodes per coarse bucket (col>>7)
constexpr int CHUNK = 8192;  // edges per sort block
constexpr int NBMAX = 800;   // max coarse buckets (N<=102400)

typedef __bf16 bf16x8 __attribute__((ext_vector_type(8)));
typedef float  f32x4  __attribute__((ext_vector_type(4)));

__device__ __forceinline__ ushort f2bf(float f) {
    unsigned u = __float_as_uint(f);
    unsigned r = (u + 0x7fffu + ((u >> 16) & 1u)) >> 16;   // RNE
    return (ushort)r;
}

__device__ __forceinline__ void accum8(float* a, uint4 u) {
    a[0] += __uint_as_float(u.x << 16); a[1] += __uint_as_float(u.x & 0xffff0000u);
    a[2] += __uint_as_float(u.y << 16); a[3] += __uint_as_float(u.y & 0xffff0000u);
    a[4] += __uint_as_float(u.z << 16); a[5] += __uint_as_float(u.z & 0xffff0000u);
    a[6] += __uint_as_float(u.w << 16); a[7] += __uint_as_float(u.w & 0xffff0000u);
}

// ---------------- fused: prep Wt (blocks 0..15), zero row (16), block-local
// bucket sort (17..16+GBLK). All global writes coalesced. ----------------
__global__ __launch_bounds__(256) void prep_sort_kernel(
    const float* __restrict__ W, ushort* __restrict__ Wt, ushort* __restrict__ hsb,
    const int* __restrict__ row, const int* __restrict__ col,
    uint* __restrict__ ebuf, int* __restrict__ histG, int* __restrict__ localOff,
    int n, int e, int nbv, int gblk) {
    int b = blockIdx.x, t = threadIdx.x;
    if (b < 16) {
        // Wt frag layout: g=(c*8+nf)*64+lane holds 8 contiguous-k bf16
        int g = b * 256 + t;
        int lane = g & 63, cn = g >> 6;
        int c = cn >> 3, nf = cn & 7;
        int ncol = nf * 16 + (lane & 15);
        int k0 = c * 32 + (lane >> 4) * 8;
        ushort* dst = Wt + (size_t)g * 8;
        #pragma unroll
        for (int j = 0; j < 8; ++j) dst[j] = f2bf(W[(k0 + j) * HDIM + ncol]);
        return;
    }
    if (b == 16) {
        if (t < HDIM) hsb[(size_t)n * HDIM + t] = 0;   // zero row for masked gathers
        return;
    }
    int g = b - 17;                      // sort-block id
    __shared__ uint dst[CHUNK];          // 32 KB
    __shared__ int hist[NBMAX], excl[NBMAX], cur[NBMAX];
    __shared__ int ws2[4];
    int lane = t & 63, w = t >> 6;
    for (int i = t; i < nbv; i += 256) hist[i] = 0;
    __syncthreads();
    int lo = g * CHUNK, hi = min(lo + CHUNK, e);
    for (int i = lo + t; i < hi; i += 256)
        atomicAdd(&hist[col[i] >> 7], 1);
    __syncthreads();
    // LDS exclusive scan of nbv bins (thread t owns bins [4t, 4t+4))
    {
        int b0 = t * 4;
        int h[4]; int s = 0;
        #pragma unroll
        for (int j = 0; j < 4; ++j) { h[j] = (b0 + j < nbv) ? hist[b0 + j] : 0; s += h[j]; }
        int incl = s;
        #pragma unroll
        for (int d = 1; d < 64; d <<= 1) { int u = __shfl_up(incl, d, 64); if (lane >= d) incl += u; }
        if (lane == 63) ws2[w] = incl;
        __syncthreads();
        int add = 0;
        #pragma unroll
        for (int i = 0; i < 4; ++i) if (i < w) add += ws2[i];
        int run = add + incl - s;
        #pragma unroll
        for (int j = 0; j < 4; ++j) {
            if (b0 + j < nbv) { excl[b0 + j] = run; cur[b0 + j] = run; }
            run += h[j];
        }
    }
    __syncthreads();
    // place into LDS (packed: row<<7 | col&127; bucket implicit by position)
    for (int i = lo + t; i < hi; i += 256) {
        int c = col[i];
        int bk = c >> 7;
        int p = atomicAdd(&cur[bk], 1);
        dst[p] = ((uint)row[i] << 7) | (uint)(c & 127);
    }
    __syncthreads();
    int cnt = hi - lo;
    for (int i = t; i < cnt; i += 256) ebuf[lo + i] = dst[i];          // coalesced
    for (int i = t; i < nbv; i += 256) {
        histG[i * gblk + g]    = hist[i];                              // coalesced-ish
        localOff[i * gblk + g] = excl[i];
    }
}

// ---------------- hierarchical scan (generic) ----------------
__global__ __launch_bounds__(256) void scanA_kernel(const int* __restrict__ in,
                                                    int* __restrict__ partial, int n) {
    int t = threadIdx.x, base = blockIdx.x * 1024;
    int s = 0;
    #pragma unroll
    for (int j = 0; j < 4; ++j) {
        int i = base + j * 256 + t;
        if (i < n) s += in[i];
    }
    __shared__ int ws[4];
    #pragma unroll
    for (int d = 1; d < 64; d <<= 1) s += __shfl_xor(s, d, 64);
    int lane = t & 63, w = t >> 6;
    if (lane == 0) ws[w] = s;
    __syncthreads();
    if (t == 0) partial[blockIdx.x] = ws[0] + ws[1] + ws[2] + ws[3];
}

__global__ void scanB_kernel(int* __restrict__ partial, int nb) {  // nb <= 256, 1 block
    int t = threadIdx.x;
    int v = (t < nb) ? partial[t] : 0;
    int orig = v;
    int lane = t & 63, w = t >> 6;
    #pragma unroll
    for (int d = 1; d < 64; d <<= 1) { int u = __shfl_up(v, d, 64); if (lane >= d) v += u; }
    __shared__ int ws[4];
    if (lane == 63) ws[w] = v;
    __syncthreads();
    int add = 0;
    #pragma unroll
    for (int i = 0; i < 4; ++i) if (i < w) add += ws[i];
    if (t < nb) partial[t] = v + add - orig;   // exclusive
}

__global__ __launch_bounds__(256) void scanC_kernel(const int* __restrict__ in,
                                                    const int* __restrict__ partial,
                                                    int* __restrict__ out, int n) {
    int t = threadIdx.x, base = blockIdx.x * 1024;
    int vals[4], tsum = 0;
    #pragma unroll
    for (int j = 0; j < 4; ++j) {
        int i = base + t * 4 + j;
        vals[j] = (i < n) ? in[i] : 0;
        tsum += vals[j];
    }
    int lane = t & 63, w = t >> 6;
    int incl = tsum;
    #pragma unroll
    for (int d = 1; d < 64; d <<= 1) { int u = __shfl_up(incl, d, 64); if (lane >= d) incl += u; }
    __shared__ int ws[4];
    if (lane == 63) ws[w] = incl;
    __syncthreads();
    int add = partial[blockIdx.x];
    #pragma unroll
    for (int i = 0; i < 4; ++i) if (i < w) add += ws[i];
    int run = add + incl - tsum;
    #pragma unroll
    for (int j = 0; j < 4; ++j) {
        int i = base + t * 4 + j;
        if (i < n) out[i] = run;
        run += vals[j];
    }
}

// ---------------- F: gather segments + fine counting sort + deg/offs/dinv ----------------
__global__ __launch_bounds__(256) void fine_kernel(const uint* __restrict__ ebuf,
                                                   const int* __restrict__ histG,
                                                   const int* __restrict__ localOff,
                                                   const int* __restrict__ histS,
                                                   uint* __restrict__ csr,
                                                   int* __restrict__ deg,
                                                   int* __restrict__ offs,
                                                   float* __restrict__ dinv,
                                                   int e, int nbv, int gblk, int n) {
    __shared__ uint elist[4096];
    __shared__ uint csrl[4096];
    __shared__ int hist[BK], excl[BK], cur[BK];
    int b = blockIdx.x, t = threadIdx.x;
    int seg0 = histS[b * gblk];
    int seg1 = (b + 1 < nbv) ? histS[(b + 1) * gblk] : e;
    int cnt = min(seg1 - seg0, 4096);

    if (t < BK) { hist[t] = 0; cur[t] = 0; }
    // gather this bucket's per-block segments into LDS (sub-line reads, coalesced-free)
    for (int g = t; g < gblk; g += 256) {
        int c   = histG[b * gblk + g];
        int src = g * CHUNK + localOff[b * gblk + g];
        int dst = histS[b * gblk + g] - seg0;
        for (int i = 0; i < c; ++i) elist[dst + i] = ebuf[src + i];
    }
    __syncthreads();
    for (int i = t; i < cnt; i += 256) atomicAdd(&hist[elist[i] & 127], 1);
    __syncthreads();
    if (t < 64) {                       // exclusive scan of 128 bins, wave 0
        int v0 = hist[2 * t], v1 = hist[2 * t + 1];
        int s = v0 + v1, incl = s;
        #pragma unroll
        for (int d = 1; d < 64; d <<= 1) { int u = __shfl_up(incl, d, 64); if (t >= d) incl += u; }
        int base = incl - s;
        excl[2 * t] = base; excl[2 * t + 1] = base + v0;
    }
    __syncthreads();
    for (int i = t; i < cnt; i += 256) {
        uint v = elist[i];
        int d = v & 127;
        int r = atomicAdd(&cur[d], 1);
        csrl[excl[d] + r] = v >> 7;
    }
    __syncthreads();
    for (int i = t; i < cnt; i += 256) csr[seg0 + i] = csrl[i];   // coalesced
    if (t < BK) {
        int node = b * BK + t;
        if (node < n) {
            int dg = hist[t];
            deg[node]  = dg;
            offs[node] = seg0 + excl[t];
            dinv[node] = rsqrtf((float)(dg + 1));
        }
    }
}

// ---------------- GEMM: hsb = bf16( (x @ W) * dinv[row] ), MFMA 16x16x32 ----------------

constexpr int MT = 64;
constexpr int XS_STRIDE = 264;

__global__ __launch_bounds__(256) void gemm_kernel(const float* __restrict__ x,
                                                   const ushort* __restrict__ Wt,
                                                   const float* __restrict__ dinv,
                                                   ushort* __restrict__ hsb, int n) {
    __shared__ ushort xs[MT * XS_STRIDE];
    __shared__ float sdinv[MT];
    int t = threadIdx.x, lane = t & 63, w = t >> 6;
    int row0 = blockIdx.x * MT;

    bf16x8 bfrag[8][2];
    #pragma unroll
    for (int c = 0; c < 8; ++c)
        #pragma unroll
        for (int f = 0; f < 2; ++f)
            bfrag[c][f] = *(const bf16x8*)(Wt + (size_t)(((c * 8) + (w * 2 + f)) * 64 + lane) * 8);

    #pragma unroll
    for (int i = 0; i < 16; ++i) {
        int rl = w * 16 + i;
        int gr = row0 + rl; if (gr >= n) gr = n - 1;
        float4 v = *(const float4*)(x + (size_t)gr * KDIM + lane * 4);
        ushort4 o;
        o.x = f2bf(v.x); o.y = f2bf(v.y); o.z = f2bf(v.z); o.w = f2bf(v.w);
        *(ushort4*)(xs + rl * XS_STRIDE + lane * 4) = o;
    }
    if (t < MT) { int g = row0 + t; sdinv[t] = dinv[(g < n) ? g : (n - 1)]; }
    __syncthreads();

    #pragma unroll
    for (int s = 0; s < MT / 16; ++s) {
        f32x4 acc0 = {0.f, 0.f, 0.f, 0.f}, acc1 = {0.f, 0.f, 0.f, 0.f};
        #pragma unroll
        for (int c = 0; c < 8; ++c) {
            const ushort* ap = xs + (s * 16 + (lane & 15)) * XS_STRIDE + c * 32 + (lane >> 4) * 8;
            bf16x8 afrag = *(const bf16x8*)ap;
            acc0 = __builtin_amdgcn_mfma_f32_16x16x32_bf16(afrag, bfrag[c][0], acc0, 0, 0, 0);
            acc1 = __builtin_amdgcn_mfma_f32_16x16x32_bf16(afrag, bfrag[c][1], acc1, 0, 0, 0);
        }
        #pragma unroll
        for (int reg = 0; reg < 4; ++reg) {
            int rl = s * 16 + (lane >> 4) * 4 + reg;
            int gr = row0 + rl;
            if (gr < n) {
                float d = sdinv[rl];
                int col0 = w * 32 + (lane & 15);
                hsb[(size_t)gr * HDIM + col0]      = f2bf(acc0[reg] * d);
                hsb[(size_t)gr * HDIM + col0 + 16] = f2bf(acc1[reg] * d);
            }
        }
    }
}

// ---------------- aggregation: wave/node, 4 edge-slots x 16 channel-groups ----------------

__global__ __launch_bounds__(256) void aggregate_kernel(
    const ushort* __restrict__ hsb, const int* __restrict__ offs,
    const int* __restrict__ deg, const int* __restrict__ csr,
    const float* __restrict__ dinv, const float* __restrict__ b,
    const float* __restrict__ alpha, float* __restrict__ out, int n) {
    int wv = threadIdx.x >> 6, lane = threadIdx.x & 63;
    int node = blockIdx.x * 4 + wv;
    if (node >= n) return;
    int base = offs[node], cnt = deg[node];
    int slot = lane >> 4, chg = lane & 15;
    const uint4* hs4 = (const uint4*)hsb;

    float a[8];
    #pragma unroll
    for (int i = 0; i < 8; ++i) a[i] = 0.f;

    if (slot == 0) {                        // self loop
        uint4 u = hs4[(size_t)node * 16 + chg];
        accum8(a, u);
    }

    for (int j = 0; j < cnt; j += 64) {
        int m = min(cnt - j, 64);
        int idx = (lane < m) ? (int)csr[base + j + lane] : n;   // n = zero row
        for (int g = 0; g < m; g += 16) {
            int s0 = __shfl(idx, g + slot, 64);
            int s1 = __shfl(idx, g + 4 + slot, 64);
            int s2 = __shfl(idx, g + 8 + slot, 64);
            int s3 = __shfl(idx, g + 12 + slot, 64);
            uint4 u0 = hs4[(size_t)s0 * 16 + chg];
            uint4 u1 = hs4[(size_t)s1 * 16 + chg];
            uint4 u2 = hs4[(size_t)s2 * 16 + chg];
            uint4 u3 = hs4[(size_t)s3 * 16 + chg];
            accum8(a, u0); accum8(a, u1); accum8(a, u2); accum8(a, u3);
        }
    }

    #pragma unroll
    for (int i = 0; i < 8; ++i) {
        a[i] += __shfl_xor(a[i], 16, 64);
        a[i] += __shfl_xor(a[i], 32, 64);
    }

    if (slot == 0) {
        float dc = dinv[node];
        int c0 = chg * 8;
        float o[8];
        #pragma unroll
        for (int i = 0; i < 8; ++i) {
            float v = fmaf(dc, a[i], b[c0 + i]);
            o[i] = v >= 0.f ? v : alpha[c0 + i] * v;
        }
        float* op = out + (size_t)node * HDIM + c0;
        *(float4*)op       = make_float4(o[0], o[1], o[2], o[3]);
        *(float4*)(op + 4) = make_float4(o[4], o[5], o[6], o[7]);
    }
}

// ---------------- launch ----------------

extern "C" void kernel_launch(void* const* d_in, const int* in_sizes, int n_in,
                              void* d_out, int out_size, void* d_ws, size_t ws_size,
                              hipStream_t stream) {
    const float* x     = (const float*)d_in[0];
    const int*   ei    = (const int*)d_in[1];
    const float* W     = (const float*)d_in[2];
    const float* b     = (const float*)d_in[3];
    const float* alpha = (const float*)d_in[4];
    float* out = (float*)d_out;

    int E = in_sizes[1] / 2;
    int N = in_sizes[0] / KDIM;
    int NB = (N + BK - 1) / BK;                // coarse buckets (782)
    int GBLK = (E + CHUNK - 1) / CHUNK;        // sort blocks (196)
    int SCAN_N = NB * GBLK;

    // ws: hsb bf16[(N+1)*128] | Wt bf16[32768] | dinv f32[N] | deg int[N] | offs int[N]
    //   | histG int[SCAN_N] | localOff int[SCAN_N] | histS int[SCAN_N] | partial int[512]
    //   | ebuf uint[GBLK*CHUNK] | csr uint[E]
    ushort* hsb   = (ushort*)d_ws;
    ushort* Wt    = hsb + (size_t)(N + 1) * HDIM;
    float* dinv   = (float*)(Wt + 32768);
    int* deg      = (int*)(dinv + N);
    int* offs     = deg + N;
    int* histG    = offs + N;
    int* localOff = histG + SCAN_N;
    int* histS    = localOff + SCAN_N;
    int* partial  = histS + SCAN_N;
    uint* ebuf    = (uint*)(partial + 512);
    uint* csr     = ebuf + (size_t)GBLK * CHUNK;

    const int* rowp = ei;      // sources
    const int* colp = ei + E;  // destinations

    int nbScan = (SCAN_N + 1023) / 1024;

    hipLaunchKernelGGL(prep_sort_kernel, dim3(17 + GBLK), dim3(256), 0, stream,
                       W, Wt, hsb, rowp, colp, ebuf, histG, localOff, N, E, NB, GBLK);
    hipLaunchKernelGGL(scanA_kernel, dim3(nbScan), dim3(256), 0, stream, histG, partial, SCAN_N);
    hipLaunchKernelGGL(scanB_kernel, dim3(1), dim3(256), 0, stream, partial, nbScan);
    hipLaunchKernelGGL(scanC_kernel, dim3(nbScan), dim3(256), 0, stream, histG, partial, histS, SCAN_N);
    hipLaunchKernelGGL(fine_kernel, dim3(NB), dim3(256), 0, stream,
                       ebuf, histG, localOff, histS, csr, deg, offs, dinv, E, NB, GBLK, N);
    hipLaunchKernelGGL(gemm_kernel, dim3((N + MT - 1) / MT), dim3(256), 0, stream, x, Wt, dinv, hsb, N);
    hipLaunchKernelGGL(aggregate_kernel, dim3((N + 3) / 4), dim3(256), 0, stream,
                       hsb, offs, deg, (const int*)csr, dinv, b, alpha, out, N);
}

// Round 7
// 296.162 us; speedup vs baseline: 2.1187x; 1.1278x over previous
//
#include <hip/hip_runtime.h>

constexpr int KDIM  = 256;   // input feature dim
constexpr int HDIM  = 128;   // output feature dim
constexpr int BK    = 128;   // nodes per coarse bucket (col>>7)
constexpr int CHUNK = 8192;  // edges per sort block
constexpr int NBMAX = 800;   // max coarse buckets (N<=102400)

typedef __bf16 bf16x8 __attribute__((ext_vector_type(8)));
typedef float  f32x4  __attribute__((ext_vector_type(4)));

__device__ __forceinline__ ushort f2bf(float f) {
    unsigned u = __float_as_uint(f);
    unsigned r = (u + 0x7fffu + ((u >> 16) & 1u)) >> 16;   // RNE
    return (ushort)r;
}

__device__ __forceinline__ void accum8(float* a, uint4 u) {
    a[0] += __uint_as_float(u.x << 16); a[1] += __uint_as_float(u.x & 0xffff0000u);
    a[2] += __uint_as_float(u.y << 16); a[3] += __uint_as_float(u.y & 0xffff0000u);
    a[4] += __uint_as_float(u.z << 16); a[5] += __uint_as_float(u.z & 0xffff0000u);
    a[6] += __uint_as_float(u.w << 16); a[7] += __uint_as_float(u.w & 0xffff0000u);
}

// ---------------- fused: prep Wt (blocks 0..7), zero row (8), block-local
// bucket sort (9..). 512 threads; int4 edge loads; col cached in regs. ----------------
__global__ __launch_bounds__(512) void prep_sort_kernel(
    const float* __restrict__ W, ushort* __restrict__ Wt, ushort* __restrict__ hsb,
    const int* __restrict__ row, const int* __restrict__ col,
    uint* __restrict__ ebuf, int* __restrict__ histG, int* __restrict__ localOff,
    int n, int e, int nbv, int gblk) {
    __shared__ uint dst[CHUNK];          // 32 KB
    __shared__ int hist[NBMAX], excl[NBMAX], cur[NBMAX];
    __shared__ int ws2[8];
    int b = blockIdx.x, t = threadIdx.x;
    if (b < 8) {
        // Wt frag layout: g=(c*8+nf)*64+lane holds 8 contiguous-k bf16
        int g = b * 512 + t;
        int lane = g & 63, cn = g >> 6;
        int c = cn >> 3, nf = cn & 7;
        int ncol = nf * 16 + (lane & 15);
        int k0 = c * 32 + (lane >> 4) * 8;
        ushort* dp = Wt + (size_t)g * 8;
        #pragma unroll
        for (int j = 0; j < 8; ++j) dp[j] = f2bf(W[(k0 + j) * HDIM + ncol]);
        return;
    }
    if (b == 8) {
        if (t < HDIM) hsb[(size_t)n * HDIM + t] = 0;   // zero row for masked gathers
        return;
    }
    int g = b - 9;                       // sort-block id
    int lane = t & 63, w = t >> 6;
    for (int i = t; i < nbv; i += 512) hist[i] = 0;
    __syncthreads();
    int lo = g * CHUNK, hi = min(lo + CHUNK, e);
    int colr[16];
    #pragma unroll
    for (int k = 0; k < 4; ++k) {
        int i0 = lo + (k * 512 + t) * 4;
        if (i0 + 3 < hi) {
            int4 c4 = *(const int4*)(col + i0);
            colr[k * 4 + 0] = c4.x; colr[k * 4 + 1] = c4.y;
            colr[k * 4 + 2] = c4.z; colr[k * 4 + 3] = c4.w;
            atomicAdd(&hist[c4.x >> 7], 1); atomicAdd(&hist[c4.y >> 7], 1);
            atomicAdd(&hist[c4.z >> 7], 1); atomicAdd(&hist[c4.w >> 7], 1);
        } else {
            #pragma unroll
            for (int j = 0; j < 4; ++j) {
                int i = i0 + j;
                int c = (i < hi) ? col[i] : -1;
                colr[k * 4 + j] = c;
                if (c >= 0) atomicAdd(&hist[c >> 7], 1);
            }
        }
    }
    __syncthreads();
    // LDS exclusive scan of nbv bins (thread t owns bins [2t, 2t+2))
    {
        int b0 = t * 2;
        int h0 = (b0 < nbv) ? hist[b0] : 0;
        int h1 = (b0 + 1 < nbv) ? hist[b0 + 1] : 0;
        int s = h0 + h1, incl = s;
        #pragma unroll
        for (int d = 1; d < 64; d <<= 1) { int u = __shfl_up(incl, d, 64); if (lane >= d) incl += u; }
        if (lane == 63) ws2[w] = incl;
        __syncthreads();
        int add = 0;
        #pragma unroll
        for (int i = 0; i < 8; ++i) if (i < w) add += ws2[i];
        int run = add + incl - s;
        if (b0 < nbv)     { excl[b0] = run;          cur[b0] = run; }
        if (b0 + 1 < nbv) { excl[b0 + 1] = run + h0; cur[b0 + 1] = run + h0; }
    }
    __syncthreads();
    // place into LDS (packed: row<<7 | col&127), col from registers
    #pragma unroll
    for (int k = 0; k < 4; ++k) {
        int i0 = lo + (k * 512 + t) * 4;
        if (i0 + 3 < hi) {
            int4 r4 = *(const int4*)(row + i0);
            int rr[4] = {r4.x, r4.y, r4.z, r4.w};
            #pragma unroll
            for (int j = 0; j < 4; ++j) {
                int c = colr[k * 4 + j];
                int p = atomicAdd(&cur[c >> 7], 1);
                dst[p] = ((uint)rr[j] << 7) | (uint)(c & 127);
            }
        } else {
            #pragma unroll
            for (int j = 0; j < 4; ++j) {
                int i = i0 + j, c = colr[k * 4 + j];
                if (c >= 0) {
                    int p = atomicAdd(&cur[c >> 7], 1);
                    dst[p] = ((uint)row[i] << 7) | (uint)(c & 127);
                }
            }
        }
    }
    __syncthreads();
    int cnt = hi - lo;
    for (int k = 0; k < 4; ++k) {                      // coalesced uint4 write-out
        int i0 = (k * 512 + t) * 4;
        if (i0 + 3 < cnt) *(uint4*)(ebuf + lo + i0) = *(uint4*)&dst[i0];
        else for (int j = 0; j < 4; ++j) if (i0 + j < cnt) ebuf[lo + i0 + j] = dst[i0 + j];
    }
    for (int i = t; i < nbv; i += 512) {
        histG[i * gblk + g]    = hist[i];
        localOff[i * gblk + g] = excl[i];
    }
}

// ---------------- hierarchical scan (generic) ----------------
__global__ __launch_bounds__(256) void scanA_kernel(const int* __restrict__ in,
                                                    int* __restrict__ partial, int n) {
    int t = threadIdx.x, base = blockIdx.x * 1024;
    int s = 0;
    #pragma unroll
    for (int j = 0; j < 4; ++j) {
        int i = base + j * 256 + t;
        if (i < n) s += in[i];
    }
    __shared__ int ws[4];
    #pragma unroll
    for (int d = 1; d < 64; d <<= 1) s += __shfl_xor(s, d, 64);
    int lane = t & 63, w = t >> 6;
    if (lane == 0) ws[w] = s;
    __syncthreads();
    if (t == 0) partial[blockIdx.x] = ws[0] + ws[1] + ws[2] + ws[3];
}

__global__ void scanB_kernel(int* __restrict__ partial, int nb) {  // nb <= 256, 1 block
    int t = threadIdx.x;
    int v = (t < nb) ? partial[t] : 0;
    int orig = v;
    int lane = t & 63, w = t >> 6;
    #pragma unroll
    for (int d = 1; d < 64; d <<= 1) { int u = __shfl_up(v, d, 64); if (lane >= d) v += u; }
    __shared__ int ws[4];
    if (lane == 63) ws[w] = v;
    __syncthreads();
    int add = 0;
    #pragma unroll
    for (int i = 0; i < 4; ++i) if (i < w) add += ws[i];
    if (t < nb) partial[t] = v + add - orig;   // exclusive
}

__global__ __launch_bounds__(256) void scanC_kernel(const int* __restrict__ in,
                                                    const int* __restrict__ partial,
                                                    int* __restrict__ out, int n) {
    int t = threadIdx.x, base = blockIdx.x * 1024;
    int vals[4], tsum = 0;
    #pragma unroll
    for (int j = 0; j < 4; ++j) {
        int i = base + t * 4 + j;
        vals[j] = (i < n) ? in[i] : 0;
        tsum += vals[j];
    }
    int lane = t & 63, w = t >> 6;
    int incl = tsum;
    #pragma unroll
    for (int d = 1; d < 64; d <<= 1) { int u = __shfl_up(incl, d, 64); if (lane >= d) incl += u; }
    __shared__ int ws[4];
    if (lane == 63) ws[w] = incl;
    __syncthreads();
    int add = partial[blockIdx.x];
    #pragma unroll
    for (int i = 0; i < 4; ++i) if (i < w) add += ws[i];
    int run = add + incl - tsum;
    #pragma unroll
    for (int j = 0; j < 4; ++j) {
        int i = base + t * 4 + j;
        if (i < n) out[i] = run;
        run += vals[j];
    }
}

// ---------------- F: gather segments + fine counting sort + deg/offs/dinv ----------------
__global__ __launch_bounds__(256) void fine_kernel(const uint* __restrict__ ebuf,
                                                   const int* __restrict__ histG,
                                                   const int* __restrict__ localOff,
                                                   const int* __restrict__ histS,
                                                   uint* __restrict__ csr,
                                                   int* __restrict__ deg,
                                                   int* __restrict__ offs,
                                                   float* __restrict__ dinv,
                                                   int e, int nbv, int gblk, int n) {
    __shared__ uint elist[4096];
    __shared__ uint csrl[4096];
    __shared__ int hist[BK], excl[BK], cur[BK];
    int b = blockIdx.x, t = threadIdx.x;
    int seg0 = histS[b * gblk];
    int seg1 = (b + 1 < nbv) ? histS[(b + 1) * gblk] : e;
    int cnt = min(seg1 - seg0, 4096);

    if (t < BK) { hist[t] = 0; cur[t] = 0; }
    // gather this bucket's per-block segments into LDS
    for (int g = t; g < gblk; g += 256) {
        int c   = histG[b * gblk + g];
        int src = g * CHUNK + localOff[b * gblk + g];
        int dst = histS[b * gblk + g] - seg0;
        for (int i = 0; i < c; ++i) elist[dst + i] = ebuf[src + i];
    }
    __syncthreads();
    for (int i = t; i < cnt; i += 256) atomicAdd(&hist[elist[i] & 127], 1);
    __syncthreads();
    if (t < 64) {                       // exclusive scan of 128 bins, wave 0
        int v0 = hist[2 * t], v1 = hist[2 * t + 1];
        int s = v0 + v1, incl = s;
        #pragma unroll
        for (int d = 1; d < 64; d <<= 1) { int u = __shfl_up(incl, d, 64); if (t >= d) incl += u; }
        int base = incl - s;
        excl[2 * t] = base; excl[2 * t + 1] = base + v0;
    }
    __syncthreads();
    for (int i = t; i < cnt; i += 256) {
        uint v = elist[i];
        int d = v & 127;
        int r = atomicAdd(&cur[d], 1);
        csrl[excl[d] + r] = v >> 7;
    }
    __syncthreads();
    for (int i = t; i < cnt; i += 256) csr[seg0 + i] = csrl[i];   // coalesced
    if (t < BK) {
        int node = b * BK + t;
        if (node < n) {
            int dg = hist[t];
            deg[node]  = dg;
            offs[node] = seg0 + excl[t];
            dinv[node] = rsqrtf((float)(dg + 1));
        }
    }
}

// ---------------- GEMM: hsb = bf16( (x @ W) * dinv[row] ), MFMA 16x16x32 ----------------

constexpr int MT = 64;
constexpr int XS_STRIDE = 264;

__global__ __launch_bounds__(256) void gemm_kernel(const float* __restrict__ x,
                                                   const ushort* __restrict__ Wt,
                                                   const float* __restrict__ dinv,
                                                   ushort* __restrict__ hsb, int n) {
    __shared__ ushort xs[MT * XS_STRIDE];
    __shared__ float sdinv[MT];
    int t = threadIdx.x, lane = t & 63, w = t >> 6;
    int row0 = blockIdx.x * MT;

    bf16x8 bfrag[8][2];
    #pragma unroll
    for (int c = 0; c < 8; ++c)
        #pragma unroll
        for (int f = 0; f < 2; ++f)
            bfrag[c][f] = *(const bf16x8*)(Wt + (size_t)(((c * 8) + (w * 2 + f)) * 64 + lane) * 8);

    #pragma unroll
    for (int i = 0; i < 16; ++i) {
        int rl = w * 16 + i;
        int gr = row0 + rl; if (gr >= n) gr = n - 1;
        float4 v = *(const float4*)(x + (size_t)gr * KDIM + lane * 4);
        ushort4 o;
        o.x = f2bf(v.x); o.y = f2bf(v.y); o.z = f2bf(v.z); o.w = f2bf(v.w);
        *(ushort4*)(xs + rl * XS_STRIDE + lane * 4) = o;
    }
    if (t < MT) { int g = row0 + t; sdinv[t] = dinv[(g < n) ? g : (n - 1)]; }
    __syncthreads();

    #pragma unroll
    for (int s = 0; s < MT / 16; ++s) {
        f32x4 acc0 = {0.f, 0.f, 0.f, 0.f}, acc1 = {0.f, 0.f, 0.f, 0.f};
        #pragma unroll
        for (int c = 0; c < 8; ++c) {
            const ushort* ap = xs + (s * 16 + (lane & 15)) * XS_STRIDE + c * 32 + (lane >> 4) * 8;
            bf16x8 afrag = *(const bf16x8*)ap;
            acc0 = __builtin_amdgcn_mfma_f32_16x16x32_bf16(afrag, bfrag[c][0], acc0, 0, 0, 0);
            acc1 = __builtin_amdgcn_mfma_f32_16x16x32_bf16(afrag, bfrag[c][1], acc1, 0, 0, 0);
        }
        #pragma unroll
        for (int reg = 0; reg < 4; ++reg) {
            int rl = s * 16 + (lane >> 4) * 4 + reg;
            int gr = row0 + rl;
            if (gr < n) {
                float d = sdinv[rl];
                int col0 = w * 32 + (lane & 15);
                hsb[(size_t)gr * HDIM + col0]      = f2bf(acc0[reg] * d);
                hsb[(size_t)gr * HDIM + col0 + 16] = f2bf(acc1[reg] * d);
            }
        }
    }
}

// ---------------- aggregation: 4 nodes/wave, one 16-lane group per node ----------------
// Group gathers its node's edges 4-at-a-time (4 outstanding uint4 loads),
// loop trip = ceil(deg/4) per group; exec-mask kills finished groups.

__global__ __launch_bounds__(256) void aggregate_kernel(
    const ushort* __restrict__ hsb, const int* __restrict__ offs,
    const int* __restrict__ deg, const int* __restrict__ csr,
    const float* __restrict__ dinv, const float* __restrict__ b,
    const float* __restrict__ alpha, float* __restrict__ out, int n) {
    int wv = threadIdx.x >> 6, lane = threadIdx.x & 63;
    int grp = lane >> 4, li = lane & 15;
    int node = blockIdx.x * 16 + wv * 4 + grp;
    bool valid = node < n;
    int nd   = valid ? node : n;            // n = zero row
    int base = valid ? offs[node] : 0;
    int cnt  = valid ? deg[node] : 0;
    const uint4* hs4 = (const uint4*)hsb;

    float a[8];
    #pragma unroll
    for (int i = 0; i < 8; ++i) a[i] = 0.f;

    uint4 su = hs4[(size_t)nd * 16 + li];   // self loop
    accum8(a, su);

    for (int it = 0; it < cnt; it += 4) {
        int src_l = (li < 4 && (it + li) < cnt) ? (int)csr[base + it + li] : n;
        int s0 = __shfl(src_l, grp * 16 + 0, 64);
        int s1 = __shfl(src_l, grp * 16 + 1, 64);
        int s2 = __shfl(src_l, grp * 16 + 2, 64);
        int s3 = __shfl(src_l, grp * 16 + 3, 64);
        uint4 u0 = hs4[(size_t)s0 * 16 + li];
        uint4 u1 = hs4[(size_t)s1 * 16 + li];
        uint4 u2 = hs4[(size_t)s2 * 16 + li];
        uint4 u3 = hs4[(size_t)s3 * 16 + li];
        accum8(a, u0); accum8(a, u1); accum8(a, u2); accum8(a, u3);
    }

    if (valid) {
        float dc = dinv[node];
        int c0 = li * 8;
        float o[8];
        #pragma unroll
        for (int i = 0; i < 8; ++i) {
            float v = fmaf(dc, a[i], b[c0 + i]);
            o[i] = v >= 0.f ? v : alpha[c0 + i] * v;
        }
        float* op = out + (size_t)node * HDIM + c0;
        *(float4*)op       = make_float4(o[0], o[1], o[2], o[3]);
        *(float4*)(op + 4) = make_float4(o[4], o[5], o[6], o[7]);
    }
}

// ---------------- launch ----------------

extern "C" void kernel_launch(void* const* d_in, const int* in_sizes, int n_in,
                              void* d_out, int out_size, void* d_ws, size_t ws_size,
                              hipStream_t stream) {
    const float* x     = (const float*)d_in[0];
    const int*   ei    = (const int*)d_in[1];
    const float* W     = (const float*)d_in[2];
    const float* b     = (const float*)d_in[3];
    const float* alpha = (const float*)d_in[4];
    float* out = (float*)d_out;

    int E = in_sizes[1] / 2;
    int N = in_sizes[0] / KDIM;
    int NB = (N + BK - 1) / BK;                // coarse buckets (782)
    int GBLK = (E + CHUNK - 1) / CHUNK;        // sort blocks (196)
    int SCAN_N = NB * GBLK;

    // ws: hsb bf16[(N+1)*128] | Wt bf16[32768] | dinv f32[N] | deg int[N] | offs int[N]
    //   | histG int[SCAN_N] | localOff int[SCAN_N] | histS int[SCAN_N] | partial int[512]
    //   | ebuf uint[GBLK*CHUNK] | csr uint[E]
    ushort* hsb   = (ushort*)d_ws;
    ushort* Wt    = hsb + (size_t)(N + 1) * HDIM;
    float* dinv   = (float*)(Wt + 32768);
    int* deg      = (int*)(dinv + N);
    int* offs     = deg + N;
    int* histG    = offs + N;
    int* localOff = histG + SCAN_N;
    int* histS    = localOff + SCAN_N;
    int* partial  = histS + SCAN_N;
    uint* ebuf    = (uint*)(partial + 512);
    uint* csr     = ebuf + (size_t)GBLK * CHUNK;

    const int* rowp = ei;      // sources
    const int* colp = ei + E;  // destinations

    int nbScan = (SCAN_N + 1023) / 1024;

    hipLaunchKernelGGL(prep_sort_kernel, dim3(9 + GBLK), dim3(512), 0, stream,
                       W, Wt, hsb, rowp, colp, ebuf, histG, localOff, N, E, NB, GBLK);
    hipLaunchKernelGGL(scanA_kernel, dim3(nbScan), dim3(256), 0, stream, histG, partial, SCAN_N);
    hipLaunchKernelGGL(scanB_kernel, dim3(1), dim3(256), 0, stream, partial, nbScan);
    hipLaunchKernelGGL(scanC_kernel, dim3(nbScan), dim3(256), 0, stream, histG, partial, histS, SCAN_N);
    hipLaunchKernelGGL(fine_kernel, dim3(NB), dim3(256), 0, stream,
                       ebuf, histG, localOff, histS, csr, deg, offs, dinv, E, NB, GBLK, N);
    hipLaunchKernelGGL(gemm_kernel, dim3((N + MT - 1) / MT), dim3(256), 0, stream, x, Wt, dinv, hsb, N);
    hipLaunchKernelGGL(aggregate_kernel, dim3((N + 15) / 16), dim3(256), 0, stream,
                       hsb, offs, deg, (const int*)csr, dinv, b, alpha, out, N);
}